// Round 3
// baseline (158.088 us; speedup 1.0000x reference)
//
#include <hip/hip_runtime.h>
#include <math.h>

#define BB 2
#define II 128
#define JJ 512
#define CC 256
#define NEL (BB*II*JJ)   // 131072
#define NINF (-INFINITY)
#define K10 4.5399929762484854e-5f   // exp(-10)

// ---------------- DPP wave64 primitives ----------------
template<int CTRL, int RM = 0xf, int BM = 0xf, bool BC = true>
__device__ __forceinline__ float dppf(float x) {
    return __int_as_float(__builtin_amdgcn_update_dpp(
        0, __float_as_int(x), CTRL, RM, BM, BC));
}
__device__ __forceinline__ float wscan_incl(float x) {
    x += dppf<0x111>(x);              // row_shr:1
    x += dppf<0x112>(x);              // row_shr:2
    x += dppf<0x114>(x);              // row_shr:4
    x += dppf<0x118>(x);              // row_shr:8
    x += dppf<0x142, 0xa>(x);         // row_bcast:15 -> rows 1,3
    x += dppf<0x143, 0xc>(x);         // row_bcast:31 -> rows 2,3
    return x;
}
__device__ __forceinline__ float lane_shr1(float x) { return dppf<0x138>(x); }
__device__ __forceinline__ float bcast63(float x) {
    return __int_as_float(__builtin_amdgcn_readlane(__float_as_int(x), 63));
}

// in-lane inclusive prefix sum, tree form (depth 3)
__device__ __forceinline__ void tree_prefix8(const float x[8], float P[8]) {
    float t[8];
    t[0] = x[0];
    #pragma unroll
    for (int q = 1; q < 8; ++q) t[q] = x[q] + x[q-1];
    float u[8];
    u[0] = t[0]; u[1] = t[1];
    #pragma unroll
    for (int q = 2; q < 8; ++q) u[q] = t[q] + t[q-2];
    P[0] = u[0]; P[1] = u[1]; P[2] = u[2]; P[3] = u[3];
    #pragma unroll
    for (int q = 4; q < 8; ++q) P[q] = u[q] + u[q-4];
}

__device__ __forceinline__ void loadrow8(const float* p, float v[8]) {
    float4 a = *reinterpret_cast<const float4*>(p);
    float4 b = *reinterpret_cast<const float4*>(p + 4);
    v[0]=a.x; v[1]=a.y; v[2]=a.z; v[3]=a.w;
    v[4]=b.x; v[5]=b.y; v[6]=b.z; v[7]=b.w;
}
__device__ __forceinline__ void storerow8(float* __restrict__ p, const float v[8]) {
    *reinterpret_cast<float4*>(p)     = make_float4(v[0],v[1],v[2],v[3]);
    *reinterpret_cast<float4*>(p + 4) = make_float4(v[4],v[5],v[6],v[7]);
}

// ---------------- async global->LDS staging (the prefetch the compiler can't kill) ----------------
typedef __attribute__((address_space(1))) float gfloat;
typedef __attribute__((address_space(3))) float lfloat;
__device__ __forceinline__ void gl_lds16(const float* g, float* l) {
    // lane i of the wave writes LDS[l + i*16B] with 16B from (g + i*4 floats)
    __builtin_amdgcn_global_load_lds((gfloat*)g, (lfloat*)l, 16, 0, 0);
}
// stage one 512-float row (2KB) of E and W into LDS slots: 4 vmem ops total
__device__ __forceinline__ void stage_row(const float* gE, const float* gW,
                                          float* lE, float* lW, int lane) {
    gl_lds16(gE + lane * 4,       lE);
    gl_lds16(gE + 256 + lane * 4, lE + 256);
    gl_lds16(gW + lane * 4,       lW);
    gl_lds16(gW + 256 + lane * 4, lW + 256);
}
template<int N> __device__ __forceinline__ void waitcnt_vm() {
    asm volatile("s_waitcnt vmcnt(%0)" :: "i"(N) : "memory");
}

// ---------------- energy: tiled outer-product GEMM ----------------
__global__ __launch_bounds__(256) void energy_kernel(
        const float* __restrict__ text, const float* __restrict__ mel,
        const float* __restrict__ noise, const float* __restrict__ ratio,
        float* __restrict__ e) {
    __shared__ float melS[64][65];
    __shared__ float texS[8][65];
    int b  = blockIdx.x;
    int i0 = blockIdx.y * 8;
    int j0 = blockIdx.z * 64;
    int t = threadIdx.x;
    int jj = t & 63, ig = t >> 6;
    float acc0 = 0.f, acc1 = 0.f;
    for (int cc = 0; cc < CC; cc += 64) {
        #pragma unroll
        for (int k = 0; k < 4; ++k) {
            int idx = t + k * 256;
            int row = idx >> 4, seg = idx & 15;
            float4 v = *reinterpret_cast<const float4*>(
                mel + (size_t)(b * JJ + j0 + row) * CC + cc + seg * 4);
            melS[row][seg*4+0] = v.x; melS[row][seg*4+1] = v.y;
            melS[row][seg*4+2] = v.z; melS[row][seg*4+3] = v.w;
        }
        if (t < 128) {
            int row = t >> 4, seg = t & 15;
            float4 v = *reinterpret_cast<const float4*>(
                text + (size_t)(b * II + i0 + row) * CC + cc + seg * 4);
            texS[row][seg*4+0] = v.x; texS[row][seg*4+1] = v.y;
            texS[row][seg*4+2] = v.z; texS[row][seg*4+3] = v.w;
        }
        __syncthreads();
        #pragma unroll 8
        for (int c = 0; c < 64; ++c) {
            float m = melS[jj][c];
            acc0 = fmaf(m, texS[ig*2+0][c], acc0);
            acc1 = fmaf(m, texS[ig*2+1][c], acc1);
        }
        __syncthreads();
    }
    float temp = 0.1f + 0.9f * ratio[0];
    float rtmp = 1.0f / temp;
    int r0 = (b * II + i0 + ig*2 + 0) * JJ + j0 + jj;
    int r1 = (b * II + i0 + ig*2 + 1) * JJ + j0 + jj;
    e[r0] = (acc0 * (1.0f/256.0f) + noise[r0]) * rtmp;
    e[r1] = (acc1 * (1.0f/256.0f) + noise[r1]) * rtmp;
}

// ---------------- per row: Ee = exp(e - rowmax); Wa = 1/suffix_sum; Wb = 1/prefix_sum ----------------
__global__ __launch_bounds__(64) void dscan_kernel(
        const float* __restrict__ e, float* __restrict__ Ee,
        float* __restrict__ Wa, float* __restrict__ Wb) {
    int row = blockIdx.x;
    int lane = threadIdx.x;
    float v[8];
    loadrow8(e + row * JJ + lane * 8, v);
    float m = v[0];
    #pragma unroll
    for (int q = 1; q < 8; ++q) m = fmaxf(m, v[q]);
    #pragma unroll
    for (int d = 1; d < 64; d <<= 1) m = fmaxf(m, __shfl_xor(m, d, 64));
    float x[8];
    #pragma unroll
    for (int q = 0; q < 8; ++q) x[q] = __expf(v[q] - m);
    storerow8(Ee + row * JJ + lane * 8, x);
    float run = 0.f, P[8];
    #pragma unroll
    for (int q = 0; q < 8; ++q) { run += x[q]; P[q] = run; }
    float sc = wscan_incl(run);
    float cp = lane_shr1(sc);
    float run2 = 0.f, S[8];
    #pragma unroll
    for (int q = 7; q >= 0; --q) { run2 += x[q]; S[q] = run2; }
    float sd = run2;
    #pragma unroll
    for (int d = 1; d < 64; d <<= 1) { float o = __shfl_down(sd, d, 64); sd += (lane + d < 64) ? o : 0.0f; }
    float cs = __shfl_down(sd, 1, 64); if (lane == 63) cs = 0.f;
    float wa[8], wb[8];
    #pragma unroll
    for (int q = 0; q < 8; ++q) {
        wa[q] = 1.0f / (S[q] + cs);
        wb[q] = 1.0f / (P[q] + cp);
    }
    storerow8(Wa + row * JJ + lane * 8, wa);
    storerow8(Wb + row * JJ + lane * 8, wb);
}

// ---------------- alpha step, LDS-staged prefetch ----------------
// Per step, vmem order is [2 row stores][4 global_load_lds], pinned by the
// sched_barrier. Row i's data was staged 3 steps ago; the manual
// s_waitcnt vmcnt(VM) (VM=18 steady = 3 steps x 6 ops in flight) gates the
// ds_read. The compiler cannot sink the builtin loads (side effects) and its
// own waitcnt bookkeeping counts them consistently. ca-store excluded from
// the count (conservative under both exec-mask codegen options).
template<bool NORM, int VM>
__device__ __forceinline__ void astep(
    int i, int lane, int off, bool pf,
    const float (&pin)[8], float (&pout)[8], float& c,
    const float* cE, const float* cW,     // LDS consume row (slot i&3)
    float* lE, float* lW,                 // LDS stage slot ((i+3)&3)
    const float* __restrict__ EeB, const float* __restrict__ WaB,
    float* __restrict__ paB, float* __restrict__ caB)
{
    storerow8(paB + (size_t)(i - 1) * JJ + off, pin);   // pin holds row i-1
    if (lane == 0) caB[i - 1] = c;
    __builtin_amdgcn_sched_barrier(0);   // stores stay older than stage loads
    if (pf) stage_row(EeB + (size_t)(i + 3) * JJ, WaB + (size_t)(i + 3) * JJ, lE, lW, lane);
    waitcnt_vm<VM>();                    // row i resident in LDS beyond this point
    float CE[8], CW[8];
    loadrow8(cE + lane * 8, CE);
    loadrow8(cW + lane * 8, CW);

    float pup = lane_shr1(pin[7]);
    float y[8];
    y[0] = pup * CW[0];
    #pragma unroll
    for (int q = 1; q < 8; ++q) y[q] = pin[q-1] * CW[q];
    float zz[8];
    #pragma unroll
    for (int q = 0; q < 7; ++q) zz[q] = pin[q];
    zz[7] = (lane == 63) ? 0.0f : pin[7];
    float Y[8], Z[8];
    tree_prefix8(y, Y);
    tree_prefix8(zz, Z);
    float sy = wscan_incl(Y[7]);
    float sz = wscan_incl(Z[7]);
    float oy = lane_shr1(sy);
    float oz = lane_shr1(sz);
    float T  = bcast63(sz);
    #pragma unroll
    for (int q = 0; q < 8; ++q) {
        float S1 = oy + Y[q];                              // incl prefix of y
        float S2 = fmaxf(T - (oz + Z[q]) + zz[q], 0.0f);   // incl suffix of z
        pout[q] = fmaf(CE[q], S1, K10 * S2);
    }
    if (NORM) {
        float Tc = fmaxf(T, 1e-30f);
        float rT = __builtin_amdgcn_rcpf(Tc);
        c += __logf(Tc);                                   // record applied divisor
        #pragma unroll
        for (int q = 0; q < 8; ++q) pout[q] *= rT;
    }
}

// ---------------- beta step (reversed j on the ds_read side) ----------------
template<bool NORM, int VM>
__device__ __forceinline__ void bstep(
    int i, int lane, int off, bool pf,
    const float (&pin)[8], float (&pout)[8], float& c,
    const float* cE, const float* cW,     // LDS consume row (slot i&3), stored linear
    float* lE, float* lW,                 // LDS stage slot ((i-3)&3)
    const float* __restrict__ EeB, const float* __restrict__ WbB,
    float* __restrict__ pbB, float* __restrict__ cbB)
{
    storerow8(pbB + (size_t)(i + 1) * JJ + off, pin);   // pin holds row i+1
    if (lane == 0) cbB[i + 1] = c;
    __builtin_amdgcn_sched_barrier(0);
    if (pf) stage_row(EeB + (size_t)(i - 3) * JJ, WbB + (size_t)(i - 3) * JJ, lE, lW, lane);
    waitcnt_vm<VM>();
    // reversed read: v[q] = row[511 - 8*lane - q]
    float tE[8], tW[8], CE[8], CW[8];
    loadrow8(cE + 504 - 8 * lane, tE);
    loadrow8(cW + 504 - 8 * lane, tW);
    #pragma unroll
    for (int q = 0; q < 8; ++q) { CE[q] = tE[7-q]; CW[q] = tW[7-q]; }

    float pup = lane_shr1(pin[7]);
    float pn[8];
    pn[0] = pup;
    #pragma unroll
    for (int q = 1; q < 8; ++q) pn[q] = pin[q-1];
    float w[8];
    #pragma unroll
    for (int q = 0; q < 8; ++q) w[q] = pn[q] * CW[q];
    float W[8], N[8];
    tree_prefix8(w, W);
    tree_prefix8(pn, N);
    float sw = wscan_incl(W[7]);
    float sn = wscan_incl(N[7]);
    float ow = lane_shr1(sw);
    float on = lane_shr1(sn);
    float T  = bcast63(sn);
    #pragma unroll
    for (int q = 0; q < 8; ++q) {
        float QA = ow + W[q];                    // incl prefix of w
        float QB = fmaxf(T - (on + N[q]), 0.0f); // excl suffix of pn
        pout[q] = fmaf(CE[q], QA, K10 * QB);
    }
    if (NORM) {
        float Tc = fmaxf(T, 1e-30f);
        float rT = __builtin_amdgcn_rcpf(Tc);
        c += __logf(Tc);
        #pragma unroll
        for (int q = 0; q < 8; ++q) pout[q] *= rT;
    }
}

// ---------------- the sequential i-recursion: 4 blocks (b,dir), one wave each ----------------
__global__ __launch_bounds__(64) void scan_ab_kernel(
        const float* __restrict__ Ee, const float* __restrict__ Wa,
        const float* __restrict__ Wb,
        float* __restrict__ pa, float* __restrict__ pb,
        float* __restrict__ ca, float* __restrict__ cb) {
    __shared__ float ldsE[4][JJ];
    __shared__ float ldsW[4][JJ];
    int b = blockIdx.x >> 1, dir = blockIdx.x & 1;
    int lane = threadIdx.x, off = lane * 8;
    size_t base = (size_t)b * II * JJ;
    float p0[8], p1[8], p2[8], p3[8], c = 0.0f;

    if (dir == 0) {
        const float* EeB = Ee + base; const float* WaB = Wa + base;
        float* paB = pa + base; float* caB = ca + b * II;
        // preamble: stage rows 0..3 -> slots 0..3, drain, init p from row 0
        stage_row(EeB,                 WaB,                 &ldsE[0][0], &ldsW[0][0], lane);
        stage_row(EeB + (size_t)1*JJ,  WaB + (size_t)1*JJ,  &ldsE[1][0], &ldsW[1][0], lane);
        stage_row(EeB + (size_t)2*JJ,  WaB + (size_t)2*JJ,  &ldsE[2][0], &ldsW[2][0], lane);
        stage_row(EeB + (size_t)3*JJ,  WaB + (size_t)3*JJ,  &ldsE[3][0], &ldsW[3][0], lane);
        waitcnt_vm<0>();
        float e0[8];
        loadrow8(&ldsE[0][lane * 8], e0);
        float wa00 = ldsW[0][0];
        #pragma unroll
        for (int q = 0; q < 8; ++q) p0[q] = e0[q] * wa00;  // row 0 (stored at step 1)
        int i = 1;
        #pragma unroll 1
        for (; i + 3 <= II - 1; i += 4) {                  // steps 1..124, all prefetch
            astep<true ,18>(i,   lane, off, true, p0, p1, c, &ldsE[1][0], &ldsW[1][0], &ldsE[0][0], &ldsW[0][0], EeB, WaB, paB, caB);
            astep<false,18>(i+1, lane, off, true, p1, p2, c, &ldsE[2][0], &ldsW[2][0], &ldsE[1][0], &ldsW[1][0], EeB, WaB, paB, caB);
            astep<false,18>(i+2, lane, off, true, p2, p3, c, &ldsE[3][0], &ldsW[3][0], &ldsE[2][0], &ldsW[2][0], EeB, WaB, paB, caB);
            astep<false,18>(i+3, lane, off, true, p3, p0, c, &ldsE[0][0], &ldsW[0][0], &ldsE[3][0], &ldsW[3][0], EeB, WaB, paB, caB);
        }
        // epilogue steps 125,126,127: no prefetch; waits tighten 14/10/6
        astep<true ,14>(125, lane, off, false, p0, p1, c, &ldsE[1][0], &ldsW[1][0], &ldsE[0][0], &ldsW[0][0], EeB, WaB, paB, caB);
        astep<false,10>(126, lane, off, false, p1, p2, c, &ldsE[2][0], &ldsW[2][0], &ldsE[1][0], &ldsW[1][0], EeB, WaB, paB, caB);
        astep<false, 6>(127, lane, off, false, p2, p3, c, &ldsE[3][0], &ldsW[3][0], &ldsE[2][0], &ldsW[2][0], EeB, WaB, paB, caB);
        storerow8(paB + (size_t)127 * JJ + off, p3);
        if (lane == 0) caB[127] = c;
    } else {
        const float* EeB = Ee + base; const float* WbB = Wb + base;
        float* pbB = pb + base; float* cbB = cb + b * II;
        // preamble: stage rows 126,125,124 -> slots 2,1,0 (row r -> slot r&3), drain
        stage_row(EeB + (size_t)126*JJ, WbB + (size_t)126*JJ, &ldsE[2][0], &ldsW[2][0], lane);
        stage_row(EeB + (size_t)125*JJ, WbB + (size_t)125*JJ, &ldsE[1][0], &ldsW[1][0], lane);
        stage_row(EeB + (size_t)124*JJ, WbB + (size_t)124*JJ, &ldsE[0][0], &ldsW[0][0], lane);
        waitcnt_vm<0>();
        #pragma unroll
        for (int q = 0; q < 8; ++q) p0[q] = 0.0f;
        p0[0] = (lane == 0) ? 1.0f : 0.0f;  // j'=0 <-> orig j=J-1 ; row 127 (stored at step 126)
        int i = II - 2;                     // 126
        #pragma unroll 1
        for (; i - 3 >= 0; i -= 4) {        // steps 126..3, all prefetch (last loads row 0)
            bstep<true ,18>(i,   lane, off, true, p0, p1, c, &ldsE[2][0], &ldsW[2][0], &ldsE[3][0], &ldsW[3][0], EeB, WbB, pbB, cbB);
            bstep<false,18>(i-1, lane, off, true, p1, p2, c, &ldsE[1][0], &ldsW[1][0], &ldsE[2][0], &ldsW[2][0], EeB, WbB, pbB, cbB);
            bstep<false,18>(i-2, lane, off, true, p2, p3, c, &ldsE[0][0], &ldsW[0][0], &ldsE[1][0], &ldsW[1][0], EeB, WbB, pbB, cbB);
            bstep<false,18>(i-3, lane, off, true, p3, p0, c, &ldsE[3][0], &ldsW[3][0], &ldsE[0][0], &ldsW[0][0], EeB, WbB, pbB, cbB);
        }
        // epilogue steps 2,1,0
        bstep<true ,14>(2, lane, off, false, p0, p1, c, &ldsE[2][0], &ldsW[2][0], &ldsE[3][0], &ldsW[3][0], EeB, WbB, pbB, cbB);
        bstep<false,10>(1, lane, off, false, p1, p2, c, &ldsE[1][0], &ldsW[1][0], &ldsE[2][0], &ldsW[2][0], EeB, WbB, pbB, cbB);
        bstep<false, 6>(0, lane, off, false, p2, p3, c, &ldsE[0][0], &ldsW[0][0], &ldsE[1][0], &ldsW[1][0], EeB, WbB, pbB, cbB);
        storerow8(pbB + off, p3);           // row 0
        if (lane == 0) cbB[0] = c;
    }
}

// ---------------- fused gamma + expand ----------------
__global__ __launch_bounds__(256) void gamma_expand_kernel(
        const float* __restrict__ pa, const float* __restrict__ pb,
        const float* __restrict__ ca, const float* __restrict__ cb,
        const float* __restrict__ text, const float* __restrict__ mmask,
        float* __restrict__ gamma_out, float* __restrict__ expanded) {
    __shared__ float wt[II][9];      // stride 9: phase-A writes ~2-way conflicts (free)
    __shared__ float Ei[II];
    __shared__ float red[8][33];     // partial column sums [q][ic]
    int b   = blockIdx.x >> 6;       // 64 tiles per batch
    int jj0 = (blockIdx.x & 63) * 8;
    int t = threadIdx.x;
    int q = t & 7, ic = t >> 3;      // ic 0..31 handles i = 4*ic..4*ic+3

    if (t < II) Ei[t] = ca[b*II + t] + cb[b*II + t];
    __syncthreads();
    float maxc = Ei[0];
    #pragma unroll 16
    for (int i = 1; i < II; ++i) maxc = fmaxf(maxc, Ei[i]);
    __syncthreads();
    if (t < II) Ei[t] = __expf(Ei[t] - maxc);
    __syncthreads();

    size_t idx0  = (size_t)b * II * JJ + jj0 + q;
    size_t idx0r = (size_t)b * II * JJ + (JJ - 1 - jj0 - q);   // pb stored j-reversed
    float d = 0.f;
    #pragma unroll
    for (int k = 0; k < 4; ++k) {
        int i = ic * 4 + k;
        float P = pa[idx0 + (size_t)i * JJ] * pb[idx0r + (size_t)i * JJ] * Ei[i];
        wt[i][q] = P;
        d += P;
    }
    red[q][ic] = d;
    __syncthreads();
    if (t < 8) {
        float s = 0.f;
        #pragma unroll
        for (int k = 0; k < 32; ++k) s += red[t][k];
        red[t][32] = 1.0f / fmaxf(s, 1e-37f);
    }
    __syncthreads();
    float rD = red[q][32];
    #pragma unroll
    for (int k = 0; k < 4; ++k) {
        int i = ic * 4 + k;
        float P = wt[i][q] * rD;
        wt[i][q] = P;
        gamma_out[idx0 + (size_t)i * JJ] = fmaxf(__logf(P), -1e30f);  // log(0)=-inf -> -1e30
    }
    __syncthreads();

    // phase B: expanded[b, jj0+qq, c=t] = mmask * sum_i wt[i][qq] * text[b,i,t]
    float acc[8] = {0,0,0,0,0,0,0,0};
    const float* txb = text + (size_t)b * II * CC + t;
    #pragma unroll 4
    for (int i = 0; i < II; ++i) {
        float tv = txb[(size_t)i * CC];
        #pragma unroll
        for (int qq = 0; qq < 8; ++qq) acc[qq] = fmaf(wt[i][qq], tv, acc[qq]);
    }
    #pragma unroll
    for (int qq = 0; qq < 8; ++qq) {
        expanded[(size_t)(b * JJ + jj0 + qq) * CC + t] =
            acc[qq] * mmask[b * JJ + jj0 + qq];
    }
}

extern "C" void kernel_launch(void* const* d_in, const int* in_sizes, int n_in,
                              void* d_out, int out_size, void* d_ws, size_t ws_size,
                              hipStream_t stream) {
    const float* text  = (const float*)d_in[0];
    const float* mel   = (const float*)d_in[1];
    const float* mmask = (const float*)d_in[3];
    const float* noise = (const float*)d_in[4];
    const float* ratio = (const float*)d_in[5];
    float* gamma_out = (float*)d_out;            // B*I*J floats
    float* expanded  = (float*)d_out + NEL;      // B*J*C floats

    float* ws = (float*)d_ws;
    float* Ee = ws;                  // NEL
    float* Wa = ws +   NEL;          // NEL
    float* Wb = ws + 2*NEL;          // NEL
    float* pa = ws + 3*NEL;          // NEL (aliased: e lives here pre-scan)
    float* pb = ws + 4*NEL;          // NEL (j-reversed layout)
    float* ca = ws + 5*NEL;          // BB*II
    float* cb = ws + 5*NEL + BB*II;  // BB*II
    float* e  = pa;                  // e dead once scan_ab starts writing pa

    hipLaunchKernelGGL(energy_kernel, dim3(BB, II/8, JJ/64), dim3(256), 0, stream,
                       text, mel, noise, ratio, e);
    hipLaunchKernelGGL(dscan_kernel, dim3(BB*II), dim3(64), 0, stream, e, Ee, Wa, Wb);
    hipLaunchKernelGGL(scan_ab_kernel, dim3(BB*2), dim3(64), 0, stream,
                       Ee, Wa, Wb, pa, pb, ca, cb);
    hipLaunchKernelGGL(gamma_expand_kernel, dim3(BB*64), dim3(256), 0, stream,
                       pa, pb, ca, cb, text, mmask, gamma_out, expanded);
}

// Round 4
// 147.478 us; speedup vs baseline: 1.0719x; 1.0719x over previous
//
#include <hip/hip_runtime.h>
#include <math.h>

#define BB 2
#define II 128
#define JJ 512
#define CC 256
#define NEL (BB*II*JJ)   // 131072
#define NINF (-INFINITY)
#define K10 4.5399929762484854e-5f   // exp(-10)

// ---------------- DPP wave64 primitives ----------------
template<int CTRL, int RM = 0xf, int BM = 0xf, bool BC = true>
__device__ __forceinline__ float dppf(float x) {
    return __int_as_float(__builtin_amdgcn_update_dpp(
        0, __float_as_int(x), CTRL, RM, BM, BC));
}
__device__ __forceinline__ float wscan_incl(float x) {
    x += dppf<0x111>(x);              // row_shr:1
    x += dppf<0x112>(x);              // row_shr:2
    x += dppf<0x114>(x);              // row_shr:4
    x += dppf<0x118>(x);              // row_shr:8
    x += dppf<0x142, 0xa>(x);         // row_bcast:15 -> rows 1,3
    x += dppf<0x143, 0xc>(x);         // row_bcast:31 -> rows 2,3
    return x;
}
__device__ __forceinline__ float lane_shr1(float x) { return dppf<0x138>(x); }
__device__ __forceinline__ float bcast63(float x) {
    return __int_as_float(__builtin_amdgcn_readlane(__float_as_int(x), 63));
}

// in-lane inclusive prefix sum, tree form (depth 3)
__device__ __forceinline__ void tree_prefix8(const float x[8], float P[8]) {
    float t[8];
    t[0] = x[0];
    #pragma unroll
    for (int q = 1; q < 8; ++q) t[q] = x[q] + x[q-1];
    float u[8];
    u[0] = t[0]; u[1] = t[1];
    #pragma unroll
    for (int q = 2; q < 8; ++q) u[q] = t[q] + t[q-2];
    P[0] = u[0]; P[1] = u[1]; P[2] = u[2]; P[3] = u[3];
    #pragma unroll
    for (int q = 4; q < 8; ++q) P[q] = u[q] + u[q-4];
}

__device__ __forceinline__ void loadrow8(const float* p, float v[8]) {
    float4 a = *reinterpret_cast<const float4*>(p);
    float4 b = *reinterpret_cast<const float4*>(p + 4);
    v[0]=a.x; v[1]=a.y; v[2]=a.z; v[3]=a.w;
    v[4]=b.x; v[5]=b.y; v[6]=b.z; v[7]=b.w;
}
__device__ __forceinline__ void storerow8(float* __restrict__ p, const float v[8]) {
    *reinterpret_cast<float4*>(p)     = make_float4(v[0],v[1],v[2],v[3]);
    *reinterpret_cast<float4*>(p + 4) = make_float4(v[4],v[5],v[6],v[7]);
}

// ---------------- async global->LDS staging ----------------
typedef __attribute__((address_space(1))) float gfloat;
typedef __attribute__((address_space(3))) float lfloat;
__device__ __forceinline__ void gl_lds16(const float* g, float* l) {
    __builtin_amdgcn_global_load_lds((gfloat*)g, (lfloat*)l, 16, 0, 0);
}
// stage one 512-float row (2KB) of E and W into LDS slots: 4 vmem ops
__device__ __forceinline__ void stage_row(const float* gE, const float* gW,
                                          float* lE, float* lW, int lane) {
    gl_lds16(gE + lane * 4,       lE);
    gl_lds16(gE + 256 + lane * 4, lE + 256);
    gl_lds16(gW + lane * 4,       lW);
    gl_lds16(gW + 256 + lane * 4, lW + 256);
}
template<int N> __device__ __forceinline__ void waitcnt_vm() {
    asm volatile("s_waitcnt vmcnt(%0)" :: "i"(N) : "memory");
}

// ---------------- energy: tiled outer-product GEMM ----------------
__global__ __launch_bounds__(256) void energy_kernel(
        const float* __restrict__ text, const float* __restrict__ mel,
        const float* __restrict__ noise, const float* __restrict__ ratio,
        float* __restrict__ e) {
    __shared__ float melS[64][65];
    __shared__ float texS[8][65];
    int b  = blockIdx.x;
    int i0 = blockIdx.y * 8;
    int j0 = blockIdx.z * 64;
    int t = threadIdx.x;
    int jj = t & 63, ig = t >> 6;
    float acc0 = 0.f, acc1 = 0.f;
    for (int cc = 0; cc < CC; cc += 64) {
        #pragma unroll
        for (int k = 0; k < 4; ++k) {
            int idx = t + k * 256;
            int row = idx >> 4, seg = idx & 15;
            float4 v = *reinterpret_cast<const float4*>(
                mel + (size_t)(b * JJ + j0 + row) * CC + cc + seg * 4);
            melS[row][seg*4+0] = v.x; melS[row][seg*4+1] = v.y;
            melS[row][seg*4+2] = v.z; melS[row][seg*4+3] = v.w;
        }
        if (t < 128) {
            int row = t >> 4, seg = t & 15;
            float4 v = *reinterpret_cast<const float4*>(
                text + (size_t)(b * II + i0 + row) * CC + cc + seg * 4);
            texS[row][seg*4+0] = v.x; texS[row][seg*4+1] = v.y;
            texS[row][seg*4+2] = v.z; texS[row][seg*4+3] = v.w;
        }
        __syncthreads();
        #pragma unroll 8
        for (int c = 0; c < 64; ++c) {
            float m = melS[jj][c];
            acc0 = fmaf(m, texS[ig*2+0][c], acc0);
            acc1 = fmaf(m, texS[ig*2+1][c], acc1);
        }
        __syncthreads();
    }
    float temp = 0.1f + 0.9f * ratio[0];
    float rtmp = 1.0f / temp;
    int r0 = (b * II + i0 + ig*2 + 0) * JJ + j0 + jj;
    int r1 = (b * II + i0 + ig*2 + 1) * JJ + j0 + jj;
    e[r0] = (acc0 * (1.0f/256.0f) + noise[r0]) * rtmp;
    e[r1] = (acc1 * (1.0f/256.0f) + noise[r1]) * rtmp;
}

// ---------------- per row: Ee = exp(e - rowmax); Wa = 1/suffix_sum; Wb = 1/prefix_sum ----------------
__global__ __launch_bounds__(64) void dscan_kernel(
        const float* __restrict__ e, float* __restrict__ Ee,
        float* __restrict__ Wa, float* __restrict__ Wb) {
    int row = blockIdx.x;
    int lane = threadIdx.x;
    float v[8];
    loadrow8(e + row * JJ + lane * 8, v);
    float m = v[0];
    #pragma unroll
    for (int q = 1; q < 8; ++q) m = fmaxf(m, v[q]);
    #pragma unroll
    for (int d = 1; d < 64; d <<= 1) m = fmaxf(m, __shfl_xor(m, d, 64));
    float x[8];
    #pragma unroll
    for (int q = 0; q < 8; ++q) x[q] = __expf(v[q] - m);
    storerow8(Ee + row * JJ + lane * 8, x);
    float run = 0.f, P[8];
    #pragma unroll
    for (int q = 0; q < 8; ++q) { run += x[q]; P[q] = run; }
    float sc = wscan_incl(run);
    float cp = lane_shr1(sc);
    float run2 = 0.f, S[8];
    #pragma unroll
    for (int q = 7; q >= 0; --q) { run2 += x[q]; S[q] = run2; }
    float sd = run2;
    #pragma unroll
    for (int d = 1; d < 64; d <<= 1) { float o = __shfl_down(sd, d, 64); sd += (lane + d < 64) ? o : 0.0f; }
    float cs = __shfl_down(sd, 1, 64); if (lane == 63) cs = 0.f;
    float wa[8], wb[8];
    #pragma unroll
    for (int q = 0; q < 8; ++q) {
        wa[q] = 1.0f / (S[q] + cs);
        wb[q] = 1.0f / (P[q] + cp);
    }
    storerow8(Wa + row * JJ + lane * 8, wa);
    storerow8(Wb + row * JJ + lane * 8, wb);
}

// ======================= scan_ab: exact-counted LDS pipeline =======================
// vmcnt retires IN ISSUE ORDER: any wait that needs a load retired transitively
// needs all older stores retired. Design invariants:
//  - per-step vmem stream = [2 p-row stores][4 stage loads], nothing else
//    (ca/cb go to LDS: lgkm domain, invisible to vmcnt)
//  - ring depth 8, stage distance 7; steady wait vmcnt(36) == "row i+1's stage
//    (6 steps old) retired" -> never waits on a store younger than 7 steps
//  - CE/CW double-buffered in regs, ds_read issued one step ahead (lgkm ~140cy
//    hides under compute)
//  - p-ring depth 8: store-source regs overwritten 7 steps after their store
// Epilogue waits (no stage issued): exact counts 32/28/24/20/16/12.

template<bool NORM, int VM, bool PF, bool PRELOAD>
__device__ __forceinline__ void astep(
    int i, int lane, int off,
    const float (&pin)[8], float (&pout)[8], float& c,
    const float (&CE)[8], const float (&CW)[8],
    float (&NE)[8], float (&NW)[8],
    float (*ldsE)[JJ], float (*ldsW)[JJ], float* ldsC,
    const float* __restrict__ EeB, const float* __restrict__ WaB,
    float* __restrict__ paB)
{
    storerow8(paB + (size_t)(i - 1) * JJ + off, pin);   // pin holds row i-1
    if (lane == 0) ldsC[i - 1] = c;                     // lgkm, not vmcnt
    __builtin_amdgcn_sched_barrier(0);                  // stores older than stage
    if (PF) stage_row(EeB + (size_t)(i + 7) * JJ, WaB + (size_t)(i + 7) * JJ,
                      &ldsE[(i - 1) & 7][0], &ldsW[(i - 1) & 7][0], lane);
    if (PRELOAD) {
        waitcnt_vm<VM>();                               // row i+1 resident in LDS
        loadrow8(&ldsE[(i + 1) & 7][lane * 8], NE);
        loadrow8(&ldsW[(i + 1) & 7][lane * 8], NW);
    }

    float pup = lane_shr1(pin[7]);
    float y[8];
    y[0] = pup * CW[0];
    #pragma unroll
    for (int q = 1; q < 8; ++q) y[q] = pin[q-1] * CW[q];
    float zz[8];
    #pragma unroll
    for (int q = 0; q < 7; ++q) zz[q] = pin[q];
    zz[7] = (lane == 63) ? 0.0f : pin[7];
    float Y[8], Z[8];
    tree_prefix8(y, Y);
    tree_prefix8(zz, Z);
    float sy = wscan_incl(Y[7]);
    float sz = wscan_incl(Z[7]);
    float oy = lane_shr1(sy);
    float oz = lane_shr1(sz);
    float T  = bcast63(sz);
    #pragma unroll
    for (int q = 0; q < 8; ++q) {
        float S1 = oy + Y[q];                              // incl prefix of y
        float S2 = fmaxf(T - (oz + Z[q]) + zz[q], 0.0f);   // incl suffix of z
        pout[q] = fmaf(CE[q], S1, K10 * S2);
    }
    if (NORM) {
        float Tc = fmaxf(T, 1e-30f);
        float rT = __builtin_amdgcn_rcpf(Tc);
        c += __logf(Tc);
        #pragma unroll
        for (int q = 0; q < 8; ++q) pout[q] *= rT;
    }
}

template<bool NORM, int VM, bool PF, bool PRELOAD>
__device__ __forceinline__ void bstep(
    int i, int lane, int off,
    const float (&pin)[8], float (&pout)[8], float& c,
    const float (&CE)[8], const float (&CW)[8],
    float (&NE)[8], float (&NW)[8],
    float (*ldsE)[JJ], float (*ldsW)[JJ], float* ldsC,
    const float* __restrict__ EeB, const float* __restrict__ WbB,
    float* __restrict__ pbB)
{
    storerow8(pbB + (size_t)(i + 1) * JJ + off, pin);   // pin holds row i+1
    if (lane == 0) ldsC[i + 1] = c;
    __builtin_amdgcn_sched_barrier(0);
    if (PF) stage_row(EeB + (size_t)(i - 7) * JJ, WbB + (size_t)(i - 7) * JJ,
                      &ldsE[(i + 1) & 7][0], &ldsW[(i + 1) & 7][0], lane);
    if (PRELOAD) {
        waitcnt_vm<VM>();                               // row i-1 resident
        float tE[8], tW[8];
        loadrow8(&ldsE[(i - 1) & 7][504 - 8 * lane], tE);
        loadrow8(&ldsW[(i - 1) & 7][504 - 8 * lane], tW);
        #pragma unroll
        for (int q = 0; q < 8; ++q) { NE[q] = tE[7-q]; NW[q] = tW[7-q]; }
    }

    float pup = lane_shr1(pin[7]);
    float pn[8];
    pn[0] = pup;
    #pragma unroll
    for (int q = 1; q < 8; ++q) pn[q] = pin[q-1];
    float w[8];
    #pragma unroll
    for (int q = 0; q < 8; ++q) w[q] = pn[q] * CW[q];
    float W[8], N[8];
    tree_prefix8(w, W);
    tree_prefix8(pn, N);
    float sw = wscan_incl(W[7]);
    float sn = wscan_incl(N[7]);
    float ow = lane_shr1(sw);
    float on = lane_shr1(sn);
    float T  = bcast63(sn);
    #pragma unroll
    for (int q = 0; q < 8; ++q) {
        float QA = ow + W[q];                    // incl prefix of w
        float QB = fmaxf(T - (on + N[q]), 0.0f); // excl suffix of pn
        pout[q] = fmaf(CE[q], QA, K10 * QB);
    }
    if (NORM) {
        float Tc = fmaxf(T, 1e-30f);
        float rT = __builtin_amdgcn_rcpf(Tc);
        c += __logf(Tc);
        #pragma unroll
        for (int q = 0; q < 8; ++q) pout[q] *= rT;
    }
}

__global__ __launch_bounds__(64) void scan_ab_kernel(
        const float* __restrict__ Ee, const float* __restrict__ Wa,
        const float* __restrict__ Wb,
        float* __restrict__ pa, float* __restrict__ pb,
        float* __restrict__ ca, float* __restrict__ cb) {
    __shared__ float ldsE[8][JJ];
    __shared__ float ldsW[8][JJ];
    __shared__ float ldsC[II];
    int b = blockIdx.x >> 1, dir = blockIdx.x & 1;
    int lane = threadIdx.x, off = lane * 8;
    size_t base = (size_t)b * II * JJ;
    float P0[8],P1[8],P2[8],P3[8],P4[8],P5[8],P6[8],P7[8];
    float bE0[8], bW0[8], bE1[8], bW1[8];
    float c = 0.0f;

    if (dir == 0) {
        const float* EeB = Ee + base; const float* WaB = Wa + base;
        float* paB = pa + base; float* caB = ca + b * II;
        // preamble: stage rows 0..7 -> slots 0..7, drain, init
        #pragma unroll
        for (int r = 0; r < 8; ++r)
            stage_row(EeB + (size_t)r * JJ, WaB + (size_t)r * JJ,
                      &ldsE[r][0], &ldsW[r][0], lane);
        waitcnt_vm<0>();
        float e0[8];
        loadrow8(&ldsE[0][lane * 8], e0);
        float wa00 = ldsW[0][0];
        #pragma unroll
        for (int q = 0; q < 8; ++q) P0[q] = e0[q] * wa00;   // row 0
        loadrow8(&ldsE[1][lane * 8], bE0);                   // preload row 1 -> buf0
        loadrow8(&ldsW[1][lane * 8], bW0);
        #pragma unroll 1
        for (int d = 0; d < 15; ++d) {                       // steps 1..120
            int ib = 1 + 8 * d;
            astep<true ,36,true,true>(ib+0, lane, off, P0, P1, c, bE0,bW0, bE1,bW1, ldsE,ldsW,ldsC, EeB,WaB,paB);
            astep<false,36,true,true>(ib+1, lane, off, P1, P2, c, bE1,bW1, bE0,bW0, ldsE,ldsW,ldsC, EeB,WaB,paB);
            astep<false,36,true,true>(ib+2, lane, off, P2, P3, c, bE0,bW0, bE1,bW1, ldsE,ldsW,ldsC, EeB,WaB,paB);
            astep<false,36,true,true>(ib+3, lane, off, P3, P4, c, bE1,bW1, bE0,bW0, ldsE,ldsW,ldsC, EeB,WaB,paB);
            astep<true ,36,true,true>(ib+4, lane, off, P4, P5, c, bE0,bW0, bE1,bW1, ldsE,ldsW,ldsC, EeB,WaB,paB);
            astep<false,36,true,true>(ib+5, lane, off, P5, P6, c, bE1,bW1, bE0,bW0, ldsE,ldsW,ldsC, EeB,WaB,paB);
            astep<false,36,true,true>(ib+6, lane, off, P6, P7, c, bE0,bW0, bE1,bW1, ldsE,ldsW,ldsC, EeB,WaB,paB);
            astep<false,36,true,true>(ib+7, lane, off, P7, P0, c, bE1,bW1, bE0,bW0, ldsE,ldsW,ldsC, EeB,WaB,paB);
        }
        // tail steps 121..127: no stage; exact waits
        astep<true ,32,false,true >(121, lane, off, P0, P1, c, bE0,bW0, bE1,bW1, ldsE,ldsW,ldsC, EeB,WaB,paB);
        astep<false,28,false,true >(122, lane, off, P1, P2, c, bE1,bW1, bE0,bW0, ldsE,ldsW,ldsC, EeB,WaB,paB);
        astep<false,24,false,true >(123, lane, off, P2, P3, c, bE0,bW0, bE1,bW1, ldsE,ldsW,ldsC, EeB,WaB,paB);
        astep<false,20,false,true >(124, lane, off, P3, P4, c, bE1,bW1, bE0,bW0, ldsE,ldsW,ldsC, EeB,WaB,paB);
        astep<true ,16,false,true >(125, lane, off, P4, P5, c, bE0,bW0, bE1,bW1, ldsE,ldsW,ldsC, EeB,WaB,paB);
        astep<false,12,false,true >(126, lane, off, P5, P6, c, bE1,bW1, bE0,bW0, ldsE,ldsW,ldsC, EeB,WaB,paB);
        astep<false, 0,false,false>(127, lane, off, P6, P7, c, bE0,bW0, bE1,bW1, ldsE,ldsW,ldsC, EeB,WaB,paB);
        storerow8(paB + (size_t)127 * JJ + off, P7);
        if (lane == 0) ldsC[127] = c;
        caB[lane]      = ldsC[lane];
        caB[lane + 64] = ldsC[lane + 64];
    } else {
        const float* EeB = Ee + base; const float* WbB = Wb + base;
        float* pbB = pb + base; float* cbB = cb + b * II;
        // preamble: stage rows 126..120 -> slots r&7, drain, init
        #pragma unroll
        for (int r = 126; r >= 120; --r)
            stage_row(EeB + (size_t)r * JJ, WbB + (size_t)r * JJ,
                      &ldsE[r & 7][0], &ldsW[r & 7][0], lane);
        waitcnt_vm<0>();
        {   // preload row 126 (slot 6), reversed -> buf0
            float tE[8], tW[8];
            loadrow8(&ldsE[6][504 - 8 * lane], tE);
            loadrow8(&ldsW[6][504 - 8 * lane], tW);
            #pragma unroll
            for (int q = 0; q < 8; ++q) { bE0[q] = tE[7-q]; bW0[q] = tW[7-q]; }
        }
        #pragma unroll
        for (int q = 0; q < 8; ++q) P7[q] = 0.0f;
        P7[0] = (lane == 0) ? 1.0f : 0.0f;   // row 127 (j'=0 <-> orig j=J-1)
        #pragma unroll 1
        for (int d = 0; d < 15; ++d) {       // steps 126..7
            int ib = 126 - 8 * d;
            bstep<true ,36,true,true>(ib-0, lane, off, P7, P6, c, bE0,bW0, bE1,bW1, ldsE,ldsW,ldsC, EeB,WbB,pbB);
            bstep<false,36,true,true>(ib-1, lane, off, P6, P5, c, bE1,bW1, bE0,bW0, ldsE,ldsW,ldsC, EeB,WbB,pbB);
            bstep<false,36,true,true>(ib-2, lane, off, P5, P4, c, bE0,bW0, bE1,bW1, ldsE,ldsW,ldsC, EeB,WbB,pbB);
            bstep<false,36,true,true>(ib-3, lane, off, P4, P3, c, bE1,bW1, bE0,bW0, ldsE,ldsW,ldsC, EeB,WbB,pbB);
            bstep<true ,36,true,true>(ib-4, lane, off, P3, P2, c, bE0,bW0, bE1,bW1, ldsE,ldsW,ldsC, EeB,WbB,pbB);
            bstep<false,36,true,true>(ib-5, lane, off, P2, P1, c, bE1,bW1, bE0,bW0, ldsE,ldsW,ldsC, EeB,WbB,pbB);
            bstep<false,36,true,true>(ib-6, lane, off, P1, P0, c, bE0,bW0, bE1,bW1, ldsE,ldsW,ldsC, EeB,WbB,pbB);
            bstep<false,36,true,true>(ib-7, lane, off, P0, P7, c, bE1,bW1, bE0,bW0, ldsE,ldsW,ldsC, EeB,WbB,pbB);
        }
        // tail steps 6..0
        bstep<true ,32,false,true >(6, lane, off, P7, P6, c, bE0,bW0, bE1,bW1, ldsE,ldsW,ldsC, EeB,WbB,pbB);
        bstep<false,28,false,true >(5, lane, off, P6, P5, c, bE1,bW1, bE0,bW0, ldsE,ldsW,ldsC, EeB,WbB,pbB);
        bstep<false,24,false,true >(4, lane, off, P5, P4, c, bE0,bW0, bE1,bW1, ldsE,ldsW,ldsC, EeB,WbB,pbB);
        bstep<false,20,false,true >(3, lane, off, P4, P3, c, bE1,bW1, bE0,bW0, ldsE,ldsW,ldsC, EeB,WbB,pbB);
        bstep<true ,16,false,true >(2, lane, off, P3, P2, c, bE0,bW0, bE1,bW1, ldsE,ldsW,ldsC, EeB,WbB,pbB);
        bstep<false,12,false,true >(1, lane, off, P2, P1, c, bE1,bW1, bE0,bW0, ldsE,ldsW,ldsC, EeB,WbB,pbB);
        bstep<false, 0,false,false>(0, lane, off, P1, P0, c, bE0,bW0, bE1,bW1, ldsE,ldsW,ldsC, EeB,WbB,pbB);
        storerow8(pbB + off, P0);           // row 0
        if (lane == 0) ldsC[0] = c;
        cbB[lane]      = ldsC[lane];
        cbB[lane + 64] = ldsC[lane + 64];
    }
}

// ---------------- fused gamma + expand ----------------
__global__ __launch_bounds__(256) void gamma_expand_kernel(
        const float* __restrict__ pa, const float* __restrict__ pb,
        const float* __restrict__ ca, const float* __restrict__ cb,
        const float* __restrict__ text, const float* __restrict__ mmask,
        float* __restrict__ gamma_out, float* __restrict__ expanded) {
    __shared__ float wt[II][9];      // stride 9: phase-A writes ~2-way conflicts (free)
    __shared__ float Ei[II];
    __shared__ float red[8][33];     // partial column sums [q][ic]
    int b   = blockIdx.x >> 6;       // 64 tiles per batch
    int jj0 = (blockIdx.x & 63) * 8;
    int t = threadIdx.x;
    int q = t & 7, ic = t >> 3;      // ic 0..31 handles i = 4*ic..4*ic+3

    if (t < II) Ei[t] = ca[b*II + t] + cb[b*II + t];
    __syncthreads();
    float maxc = Ei[0];
    #pragma unroll 16
    for (int i = 1; i < II; ++i) maxc = fmaxf(maxc, Ei[i]);
    __syncthreads();
    if (t < II) Ei[t] = __expf(Ei[t] - maxc);
    __syncthreads();

    size_t idx0  = (size_t)b * II * JJ + jj0 + q;
    size_t idx0r = (size_t)b * II * JJ + (JJ - 1 - jj0 - q);   // pb stored j-reversed
    float d = 0.f;
    #pragma unroll
    for (int k = 0; k < 4; ++k) {
        int i = ic * 4 + k;
        float P = pa[idx0 + (size_t)i * JJ] * pb[idx0r + (size_t)i * JJ] * Ei[i];
        wt[i][q] = P;
        d += P;
    }
    red[q][ic] = d;
    __syncthreads();
    if (t < 8) {
        float s = 0.f;
        #pragma unroll
        for (int k = 0; k < 32; ++k) s += red[t][k];
        red[t][32] = 1.0f / fmaxf(s, 1e-37f);
    }
    __syncthreads();
    float rD = red[q][32];
    #pragma unroll
    for (int k = 0; k < 4; ++k) {
        int i = ic * 4 + k;
        float P = wt[i][q] * rD;
        wt[i][q] = P;
        gamma_out[idx0 + (size_t)i * JJ] = fmaxf(__logf(P), -1e30f);  // log(0)=-inf -> -1e30
    }
    __syncthreads();

    // phase B: expanded[b, jj0+qq, c=t] = mmask * sum_i wt[i][qq] * text[b,i,t]
    float acc[8] = {0,0,0,0,0,0,0,0};
    const float* txb = text + (size_t)b * II * CC + t;
    #pragma unroll 4
    for (int i = 0; i < II; ++i) {
        float tv = txb[(size_t)i * CC];
        #pragma unroll
        for (int qq = 0; qq < 8; ++qq) acc[qq] = fmaf(wt[i][qq], tv, acc[qq]);
    }
    #pragma unroll
    for (int qq = 0; qq < 8; ++qq) {
        expanded[(size_t)(b * JJ + jj0 + qq) * CC + t] =
            acc[qq] * mmask[b * JJ + jj0 + qq];
    }
}

extern "C" void kernel_launch(void* const* d_in, const int* in_sizes, int n_in,
                              void* d_out, int out_size, void* d_ws, size_t ws_size,
                              hipStream_t stream) {
    const float* text  = (const float*)d_in[0];
    const float* mel   = (const float*)d_in[1];
    const float* mmask = (const float*)d_in[3];
    const float* noise = (const float*)d_in[4];
    const float* ratio = (const float*)d_in[5];
    float* gamma_out = (float*)d_out;            // B*I*J floats
    float* expanded  = (float*)d_out + NEL;      // B*J*C floats

    float* ws = (float*)d_ws;
    float* Ee = ws;                  // NEL
    float* Wa = ws +   NEL;          // NEL
    float* Wb = ws + 2*NEL;          // NEL
    float* pa = ws + 3*NEL;          // NEL (aliased: e lives here pre-scan)
    float* pb = ws + 4*NEL;          // NEL (j-reversed layout)
    float* ca = ws + 5*NEL;          // BB*II
    float* cb = ws + 5*NEL + BB*II;  // BB*II
    float* e  = pa;                  // e dead once scan_ab starts writing pa

    hipLaunchKernelGGL(energy_kernel, dim3(BB, II/8, JJ/64), dim3(256), 0, stream,
                       text, mel, noise, ratio, e);
    hipLaunchKernelGGL(dscan_kernel, dim3(BB*II), dim3(64), 0, stream, e, Ee, Wa, Wb);
    hipLaunchKernelGGL(scan_ab_kernel, dim3(BB*2), dim3(64), 0, stream,
                       Ee, Wa, Wb, pa, pb, ca, cb);
    hipLaunchKernelGGL(gamma_expand_kernel, dim3(BB*64), dim3(256), 0, stream,
                       pa, pb, ca, cb, text, mmask, gamma_out, expanded);
}

// Round 6
// 130.154 us; speedup vs baseline: 1.2146x; 1.1331x over previous
//
#include <hip/hip_runtime.h>
#include <math.h>

#define BB 2
#define II 128
#define JJ 512
#define CC 256
#define NEL (BB*II*JJ)   // 131072
#define NINF (-INFINITY)
#define K10 4.5399929762484854e-5f   // exp(-10)

typedef float f32x4 __attribute__((ext_vector_type(4)));   // asm-operand-safe vec4

// ---------------- DPP wave64 primitives ----------------
template<int CTRL, int RM = 0xf, int BM = 0xf, bool BC = true>
__device__ __forceinline__ float dppf(float x) {
    return __int_as_float(__builtin_amdgcn_update_dpp(
        0, __float_as_int(x), CTRL, RM, BM, BC));
}
__device__ __forceinline__ float wscan_incl(float x) {
    x += dppf<0x111>(x);              // row_shr:1
    x += dppf<0x112>(x);              // row_shr:2
    x += dppf<0x114>(x);              // row_shr:4
    x += dppf<0x118>(x);              // row_shr:8
    x += dppf<0x142, 0xa>(x);         // row_bcast:15 -> rows 1,3
    x += dppf<0x143, 0xc>(x);         // row_bcast:31 -> rows 2,3
    return x;
}
__device__ __forceinline__ float lane_shr1(float x) { return dppf<0x138>(x); }
__device__ __forceinline__ float bcast63(float x) {
    return __int_as_float(__builtin_amdgcn_readlane(__float_as_int(x), 63));
}

// in-lane inclusive prefix sum, tree form (depth 3)
__device__ __forceinline__ void tree_prefix8(const float x[8], float P[8]) {
    float t[8];
    t[0] = x[0];
    #pragma unroll
    for (int q = 1; q < 8; ++q) t[q] = x[q] + x[q-1];
    float u[8];
    u[0] = t[0]; u[1] = t[1];
    #pragma unroll
    for (int q = 2; q < 8; ++q) u[q] = t[q] + t[q-2];
    P[0] = u[0]; P[1] = u[1]; P[2] = u[2]; P[3] = u[3];
    #pragma unroll
    for (int q = 4; q < 8; ++q) P[q] = u[q] + u[q-4];
}

__device__ __forceinline__ void loadrow8(const float* p, float v[8]) {
    float4 a = *reinterpret_cast<const float4*>(p);
    float4 b = *reinterpret_cast<const float4*>(p + 4);
    v[0]=a.x; v[1]=a.y; v[2]=a.z; v[3]=a.w;
    v[4]=b.x; v[5]=b.y; v[6]=b.z; v[7]=b.w;
}
__device__ __forceinline__ void storerow8(float* __restrict__ p, const float v[8]) {
    *reinterpret_cast<float4*>(p)     = make_float4(v[0],v[1],v[2],v[3]);
    *reinterpret_cast<float4*>(p + 4) = make_float4(v[4],v[5],v[6],v[7]);
}

// ---------------- hand-held vmem ops (invisible to SIInsertWaitcnts) ----------------
// All loop-body vmem is inline asm so the compiler inserts NO vmcnt waits of its
// own (its counting is blind to asm ops and would otherwise drain the pipeline).
__device__ __forceinline__ void aload2(f32x4 &d0, f32x4 &d1, const float* p) {
    asm volatile("global_load_dwordx4 %0, %2, off\n\t"
                 "global_load_dwordx4 %1, %2, off offset:16"
                 : "=&v"(d0), "=&v"(d1) : "v"(p) : "memory");
}
__device__ __forceinline__ void astore2(f32x4 d0, f32x4 d1, float* p) {
    asm volatile("global_store_dwordx4 %2, %0, off\n\t"
                 "global_store_dwordx4 %2, %1, off offset:16"
                 :: "v"(d0), "v"(d1), "v"(p) : "memory");
}
template<int N> __device__ __forceinline__ void waitcnt_vm() {
    asm volatile("s_waitcnt vmcnt(%0)" :: "i"(N) : "memory");
}

struct Buf { f32x4 e0, e1, w0, w1; };   // one (Ee,W) row fragment: 16 VGPRs

// ---------------- energy: tiled outer-product GEMM ----------------
__global__ __launch_bounds__(256) void energy_kernel(
        const float* __restrict__ text, const float* __restrict__ mel,
        const float* __restrict__ noise, const float* __restrict__ ratio,
        float* __restrict__ e) {
    __shared__ float melS[64][65];
    __shared__ float texS[8][65];
    int b  = blockIdx.x;
    int i0 = blockIdx.y * 8;
    int j0 = blockIdx.z * 64;
    int t = threadIdx.x;
    int jj = t & 63, ig = t >> 6;
    float acc0 = 0.f, acc1 = 0.f;
    for (int cc = 0; cc < CC; cc += 64) {
        #pragma unroll
        for (int k = 0; k < 4; ++k) {
            int idx = t + k * 256;
            int row = idx >> 4, seg = idx & 15;
            float4 v = *reinterpret_cast<const float4*>(
                mel + (size_t)(b * JJ + j0 + row) * CC + cc + seg * 4);
            melS[row][seg*4+0] = v.x; melS[row][seg*4+1] = v.y;
            melS[row][seg*4+2] = v.z; melS[row][seg*4+3] = v.w;
        }
        if (t < 128) {
            int row = t >> 4, seg = t & 15;
            float4 v = *reinterpret_cast<const float4*>(
                text + (size_t)(b * II + i0 + row) * CC + cc + seg * 4);
            texS[row][seg*4+0] = v.x; texS[row][seg*4+1] = v.y;
            texS[row][seg*4+2] = v.z; texS[row][seg*4+3] = v.w;
        }
        __syncthreads();
        #pragma unroll 8
        for (int c = 0; c < 64; ++c) {
            float m = melS[jj][c];
            acc0 = fmaf(m, texS[ig*2+0][c], acc0);
            acc1 = fmaf(m, texS[ig*2+1][c], acc1);
        }
        __syncthreads();
    }
    float temp = 0.1f + 0.9f * ratio[0];
    float rtmp = 1.0f / temp;
    int r0 = (b * II + i0 + ig*2 + 0) * JJ + j0 + jj;
    int r1 = (b * II + i0 + ig*2 + 1) * JJ + j0 + jj;
    e[r0] = (acc0 * (1.0f/256.0f) + noise[r0]) * rtmp;
    e[r1] = (acc1 * (1.0f/256.0f) + noise[r1]) * rtmp;
}

// ---------------- per row: Ee = exp(e - rowmax); Wa = 1/suffix_sum; Wb = 1/prefix_sum ----------------
__global__ __launch_bounds__(64) void dscan_kernel(
        const float* __restrict__ e, float* __restrict__ Ee,
        float* __restrict__ Wa, float* __restrict__ Wb) {
    int row = blockIdx.x;
    int lane = threadIdx.x;
    float v[8];
    loadrow8(e + row * JJ + lane * 8, v);
    float m = v[0];
    #pragma unroll
    for (int q = 1; q < 8; ++q) m = fmaxf(m, v[q]);
    #pragma unroll
    for (int d = 1; d < 64; d <<= 1) m = fmaxf(m, __shfl_xor(m, d, 64));
    float x[8];
    #pragma unroll
    for (int q = 0; q < 8; ++q) x[q] = __expf(v[q] - m);
    storerow8(Ee + row * JJ + lane * 8, x);
    float run = 0.f, P[8];
    #pragma unroll
    for (int q = 0; q < 8; ++q) { run += x[q]; P[q] = run; }
    float sc = wscan_incl(run);
    float cp = lane_shr1(sc);
    float run2 = 0.f, S[8];
    #pragma unroll
    for (int q = 7; q >= 0; --q) { run2 += x[q]; S[q] = run2; }
    float sd = run2;
    #pragma unroll
    for (int d = 1; d < 64; d <<= 1) { float o = __shfl_down(sd, d, 64); sd += (lane + d < 64) ? o : 0.0f; }
    float cs = __shfl_down(sd, 1, 64); if (lane == 63) cs = 0.f;
    float wa[8], wb[8];
    #pragma unroll
    for (int q = 0; q < 8; ++q) {
        wa[q] = 1.0f / (S[q] + cs);
        wb[q] = 1.0f / (P[q] + cp);
    }
    storerow8(Wa + row * JJ + lane * 8, wa);
    storerow8(Wb + row * JJ + lane * 8, wb);
}

// ======================= scan_ab: all-asm vmem, reg-resident prefetch d=3 =======================
// Per step, vmem (all inline asm, exact order): [2 stores][4 loads][wait vmcnt(VM)].
// Steady VM=18 == "row i's loads (3 steps old) retired"; warm-up 14/16; drain 14/10/6.
// ca/cb accumulate in LDS (lgkm domain, not in the vmcnt stream).
// p-state rotates depth 4: P regs redefined at step i were stored at step i-3,
// already retired by this step's wait.

template<bool NORM, int VM, bool PF>
__device__ __forceinline__ void astep(
    int i, int lane, int off,
    const float (&pin)[8], float (&pout)[8], float& c,
    Buf& C, Buf& L,
    const float* __restrict__ EeB, const float* __restrict__ WaB,
    float* __restrict__ paB, float* ldsC)
{
    {
        f32x4 s0 = {pin[0], pin[1], pin[2], pin[3]};
        f32x4 s1 = {pin[4], pin[5], pin[6], pin[7]};
        astore2(s0, s1, paB + (size_t)(i - 1) * JJ + off);   // pin holds row i-1
    }
    if (lane == 0) ldsC[i - 1] = c;
    if (PF) {
        aload2(L.e0, L.e1, EeB + (size_t)(i + 3) * JJ + off);
        aload2(L.w0, L.w1, WaB + (size_t)(i + 3) * JJ + off);
    }
    waitcnt_vm<VM>();
    __builtin_amdgcn_sched_barrier(0);   // rule #18: keep consumers behind the wait
    float CE[8] = {C.e0[0],C.e0[1],C.e0[2],C.e0[3],C.e1[0],C.e1[1],C.e1[2],C.e1[3]};
    float CW[8] = {C.w0[0],C.w0[1],C.w0[2],C.w0[3],C.w1[0],C.w1[1],C.w1[2],C.w1[3]};

    float pup = lane_shr1(pin[7]);
    float y[8];
    y[0] = pup * CW[0];
    #pragma unroll
    for (int q = 1; q < 8; ++q) y[q] = pin[q-1] * CW[q];
    float zz[8];
    #pragma unroll
    for (int q = 0; q < 7; ++q) zz[q] = pin[q];
    zz[7] = (lane == 63) ? 0.0f : pin[7];
    float Y[8], Z[8];
    tree_prefix8(y, Y);
    tree_prefix8(zz, Z);
    float sy = wscan_incl(Y[7]);
    float sz = wscan_incl(Z[7]);
    float oy = lane_shr1(sy);
    float oz = lane_shr1(sz);
    float T  = bcast63(sz);
    #pragma unroll
    for (int q = 0; q < 8; ++q) {
        float S1 = oy + Y[q];                              // incl prefix of y
        float S2 = fmaxf(T - (oz + Z[q]) + zz[q], 0.0f);   // incl suffix of z
        pout[q] = fmaf(CE[q], S1, K10 * S2);
    }
    if (NORM) {
        float Tc = fmaxf(T, 1e-30f);
        float rT = __builtin_amdgcn_rcpf(Tc);
        c += __logf(Tc);
        #pragma unroll
        for (int q = 0; q < 8; ++q) pout[q] *= rT;
    }
}

template<bool NORM, int VM, bool PF>
__device__ __forceinline__ void bstep(
    int i, int lane, int off,
    const float (&pin)[8], float (&pout)[8], float& c,
    Buf& C, Buf& L,
    const float* __restrict__ EeB, const float* __restrict__ WbB,
    float* __restrict__ pbB, float* ldsC)
{
    {
        f32x4 s0 = {pin[0], pin[1], pin[2], pin[3]};
        f32x4 s1 = {pin[4], pin[5], pin[6], pin[7]};
        astore2(s0, s1, pbB + (size_t)(i + 1) * JJ + off);   // pin holds row i+1
    }
    if (lane == 0) ldsC[i + 1] = c;
    if (PF) {
        aload2(L.e0, L.e1, EeB + (size_t)(i - 3) * JJ + 504 - 8 * lane);
        aload2(L.w0, L.w1, WbB + (size_t)(i - 3) * JJ + 504 - 8 * lane);
    }
    waitcnt_vm<VM>();
    __builtin_amdgcn_sched_barrier(0);
    // reversed: CE[q] = rowdata[7-q]  (rowdata[k] = row[504-8*lane+k])
    float CE[8] = {C.e1[3],C.e1[2],C.e1[1],C.e1[0],C.e0[3],C.e0[2],C.e0[1],C.e0[0]};
    float CW[8] = {C.w1[3],C.w1[2],C.w1[1],C.w1[0],C.w0[3],C.w0[2],C.w0[1],C.w0[0]};

    float pup = lane_shr1(pin[7]);
    float pn[8];
    pn[0] = pup;
    #pragma unroll
    for (int q = 1; q < 8; ++q) pn[q] = pin[q-1];
    float w[8];
    #pragma unroll
    for (int q = 0; q < 8; ++q) w[q] = pn[q] * CW[q];
    float W[8], N[8];
    tree_prefix8(w, W);
    tree_prefix8(pn, N);
    float sw = wscan_incl(W[7]);
    float sn = wscan_incl(N[7]);
    float ow = lane_shr1(sw);
    float on = lane_shr1(sn);
    float T  = bcast63(sn);
    #pragma unroll
    for (int q = 0; q < 8; ++q) {
        float QA = ow + W[q];                    // incl prefix of w
        float QB = fmaxf(T - (on + N[q]), 0.0f); // excl suffix of pn
        pout[q] = fmaf(CE[q], QA, K10 * QB);
    }
    if (NORM) {
        float Tc = fmaxf(T, 1e-30f);
        float rT = __builtin_amdgcn_rcpf(Tc);
        c += __logf(Tc);
        #pragma unroll
        for (int q = 0; q < 8; ++q) pout[q] *= rT;
    }
}

__global__ __launch_bounds__(64) void scan_ab_kernel(
        const float* __restrict__ Ee, const float* __restrict__ Wa,
        const float* __restrict__ Wb,
        float* __restrict__ pa, float* __restrict__ pb,
        float* __restrict__ ca, float* __restrict__ cb) {
    __shared__ float ldsC[II];
    int b = blockIdx.x >> 1, dir = blockIdx.x & 1;
    int lane = threadIdx.x, off = lane * 8;
    size_t base = (size_t)b * II * JJ;
    float P0[8], P1[8], P2[8], P3[8], c = 0.0f;
    Buf B0, B1, B2, B3;

    if (dir == 0) {
        const float* EeB = Ee + base; const float* WaB = Wa + base;
        float* paB = pa + base; float* caB = ca + b * II;
        // row 0 via compiler loads (their auto-waits stay ABOVE our asm stream)
        float e0r[8];
        loadrow8(EeB + off, e0r);
        float wa00 = WaB[0];
        #pragma unroll
        for (int q = 0; q < 8; ++q) P0[q] = e0r[q] * wa00;   // row 0
        __builtin_amdgcn_sched_barrier(0);
        // asm prefetch rows 1,2,3 -> B1,B2,B3 (12 vmem ops in flight)
        aload2(B1.e0, B1.e1, EeB + (size_t)1*JJ + off); aload2(B1.w0, B1.w1, WaB + (size_t)1*JJ + off);
        aload2(B2.e0, B2.e1, EeB + (size_t)2*JJ + off); aload2(B2.w0, B2.w1, WaB + (size_t)2*JJ + off);
        aload2(B3.e0, B3.e1, EeB + (size_t)3*JJ + off); aload2(B3.w0, B3.w1, WaB + (size_t)3*JJ + off);
        // warm-up (exact counts)
        astep<true ,14,true>(1, lane, off, P0, P1, c, B1, B0, EeB, WaB, paB, ldsC);
        astep<false,16,true>(2, lane, off, P1, P2, c, B2, B1, EeB, WaB, paB, ldsC);
        #pragma unroll 1
        for (int d = 0; d < 15; ++d) {        // steps 3..122
            int ib = 3 + 8 * d;
            astep<false,18,true>(ib+0, lane, off, P2, P3, c, B3, B2, EeB, WaB, paB, ldsC);
            astep<false,18,true>(ib+1, lane, off, P3, P0, c, B0, B3, EeB, WaB, paB, ldsC);
            astep<true ,18,true>(ib+2, lane, off, P0, P1, c, B1, B0, EeB, WaB, paB, ldsC);
            astep<false,18,true>(ib+3, lane, off, P1, P2, c, B2, B1, EeB, WaB, paB, ldsC);
            astep<false,18,true>(ib+4, lane, off, P2, P3, c, B3, B2, EeB, WaB, paB, ldsC);
            astep<false,18,true>(ib+5, lane, off, P3, P0, c, B0, B3, EeB, WaB, paB, ldsC);
            astep<true ,18,true>(ib+6, lane, off, P0, P1, c, B1, B0, EeB, WaB, paB, ldsC);
            astep<false,18,true>(ib+7, lane, off, P1, P2, c, B2, B1, EeB, WaB, paB, ldsC);
        }
        astep<false,18,true >(123, lane, off, P2, P3, c, B3, B2, EeB, WaB, paB, ldsC);
        astep<false,18,true >(124, lane, off, P3, P0, c, B0, B3, EeB, WaB, paB, ldsC);
        astep<true ,14,false>(125, lane, off, P0, P1, c, B1, B0, EeB, WaB, paB, ldsC);
        astep<false,10,false>(126, lane, off, P1, P2, c, B2, B1, EeB, WaB, paB, ldsC);
        astep<false, 6,false>(127, lane, off, P2, P3, c, B3, B2, EeB, WaB, paB, ldsC);
        storerow8(paB + (size_t)127 * JJ + off, P3);
        if (lane == 0) ldsC[127] = c;
        waitcnt_vm<0>();                       // drain our asm stores before endpgm
        caB[lane]      = ldsC[lane];
        caB[lane + 64] = ldsC[lane + 64];
    } else {
        const float* EeB = Ee + base; const float* WbB = Wb + base;
        float* pbB = pb + base; float* cbB = cb + b * II;
        #pragma unroll
        for (int q = 0; q < 8; ++q) P3[q] = 0.0f;
        P3[0] = (lane == 0) ? 1.0f : 0.0f;   // row 127 (j'=0 <-> orig j=J-1)
        // asm prefetch rows 126,125,124 -> B2,B1,B0 (reversed addressing)
        aload2(B2.e0, B2.e1, EeB + (size_t)126*JJ + 504 - 8*lane); aload2(B2.w0, B2.w1, WbB + (size_t)126*JJ + 504 - 8*lane);
        aload2(B1.e0, B1.e1, EeB + (size_t)125*JJ + 504 - 8*lane); aload2(B1.w0, B1.w1, WbB + (size_t)125*JJ + 504 - 8*lane);
        aload2(B0.e0, B0.e1, EeB + (size_t)124*JJ + 504 - 8*lane); aload2(B0.w0, B0.w1, WbB + (size_t)124*JJ + 504 - 8*lane);
        bstep<true ,14,true>(126, lane, off, P3, P2, c, B2, B3, EeB, WbB, pbB, ldsC);
        bstep<false,16,true>(125, lane, off, P2, P1, c, B1, B2, EeB, WbB, pbB, ldsC);
        #pragma unroll 1
        for (int d = 0; d < 15; ++d) {        // steps 124..5
            int ib = 124 - 8 * d;
            bstep<false,18,true>(ib-0, lane, off, P1, P0, c, B0, B1, EeB, WbB, pbB, ldsC);
            bstep<false,18,true>(ib-1, lane, off, P0, P3, c, B3, B0, EeB, WbB, pbB, ldsC);
            bstep<true ,18,true>(ib-2, lane, off, P3, P2, c, B2, B3, EeB, WbB, pbB, ldsC);
            bstep<false,18,true>(ib-3, lane, off, P2, P1, c, B1, B2, EeB, WbB, pbB, ldsC);
            bstep<false,18,true>(ib-4, lane, off, P1, P0, c, B0, B1, EeB, WbB, pbB, ldsC);
            bstep<false,18,true>(ib-5, lane, off, P0, P3, c, B3, B0, EeB, WbB, pbB, ldsC);
            bstep<true ,18,true>(ib-6, lane, off, P3, P2, c, B2, B3, EeB, WbB, pbB, ldsC);
            bstep<false,18,true>(ib-7, lane, off, P2, P1, c, B1, B2, EeB, WbB, pbB, ldsC);
        }
        bstep<false,18,true >(4, lane, off, P1, P0, c, B0, B1, EeB, WbB, pbB, ldsC);
        bstep<false,18,true >(3, lane, off, P0, P3, c, B3, B0, EeB, WbB, pbB, ldsC);
        bstep<true ,14,false>(2, lane, off, P3, P2, c, B2, B3, EeB, WbB, pbB, ldsC);
        bstep<false,10,false>(1, lane, off, P2, P1, c, B1, B2, EeB, WbB, pbB, ldsC);
        bstep<false, 6,false>(0, lane, off, P1, P0, c, B0, B1, EeB, WbB, pbB, ldsC);
        storerow8(pbB + off, P0);           // row 0
        if (lane == 0) ldsC[0] = c;
        waitcnt_vm<0>();                    // drain our asm stores before endpgm
        cbB[lane]      = ldsC[lane];
        cbB[lane + 64] = ldsC[lane + 64];
    }
}

// ---------------- fused gamma + expand ----------------
__global__ __launch_bounds__(256) void gamma_expand_kernel(
        const float* __restrict__ pa, const float* __restrict__ pb,
        const float* __restrict__ ca, const float* __restrict__ cb,
        const float* __restrict__ text, const float* __restrict__ mmask,
        float* __restrict__ gamma_out, float* __restrict__ expanded) {
    __shared__ float wt[II][9];      // stride 9: phase-A writes ~2-way conflicts (free)
    __shared__ float Ei[II];
    __shared__ float red[8][33];     // partial column sums [q][ic]
    int b   = blockIdx.x >> 6;       // 64 tiles per batch
    int jj0 = (blockIdx.x & 63) * 8;
    int t = threadIdx.x;
    int q = t & 7, ic = t >> 3;      // ic 0..31 handles i = 4*ic..4*ic+3

    if (t < II) Ei[t] = ca[b*II + t] + cb[b*II + t];
    __syncthreads();
    float maxc = Ei[0];
    #pragma unroll 16
    for (int i = 1; i < II; ++i) maxc = fmaxf(maxc, Ei[i]);
    __syncthreads();
    if (t < II) Ei[t] = __expf(Ei[t] - maxc);
    __syncthreads();

    size_t idx0  = (size_t)b * II * JJ + jj0 + q;
    size_t idx0r = (size_t)b * II * JJ + (JJ - 1 - jj0 - q);   // pb stored j-reversed
    float d = 0.f;
    #pragma unroll
    for (int k = 0; k < 4; ++k) {
        int i = ic * 4 + k;
        float P = pa[idx0 + (size_t)i * JJ] * pb[idx0r + (size_t)i * JJ] * Ei[i];
        wt[i][q] = P;
        d += P;
    }
    red[q][ic] = d;
    __syncthreads();
    if (t < 8) {
        float s = 0.f;
        #pragma unroll
        for (int k = 0; k < 32; ++k) s += red[t][k];
        red[t][32] = 1.0f / fmaxf(s, 1e-37f);
    }
    __syncthreads();
    float rD = red[q][32];
    #pragma unroll
    for (int k = 0; k < 4; ++k) {
        int i = ic * 4 + k;
        float P = wt[i][q] * rD;
        wt[i][q] = P;
        gamma_out[idx0 + (size_t)i * JJ] = fmaxf(__logf(P), -1e30f);  // log(0)=-inf -> -1e30
    }
    __syncthreads();

    // phase B: expanded[b, jj0+qq, c=t] = mmask * sum_i wt[i][qq] * text[b,i,t]
    float acc[8] = {0,0,0,0,0,0,0,0};
    const float* txb = text + (size_t)b * II * CC + t;
    #pragma unroll 4
    for (int i = 0; i < II; ++i) {
        float tv = txb[(size_t)i * CC];
        #pragma unroll
        for (int qq = 0; qq < 8; ++qq) acc[qq] = fmaf(wt[i][qq], tv, acc[qq]);
    }
    #pragma unroll
    for (int qq = 0; qq < 8; ++qq) {
        expanded[(size_t)(b * JJ + jj0 + qq) * CC + t] =
            acc[qq] * mmask[b * JJ + jj0 + qq];
    }
}

extern "C" void kernel_launch(void* const* d_in, const int* in_sizes, int n_in,
                              void* d_out, int out_size, void* d_ws, size_t ws_size,
                              hipStream_t stream) {
    const float* text  = (const float*)d_in[0];
    const float* mel   = (const float*)d_in[1];
    const float* mmask = (const float*)d_in[3];
    const float* noise = (const float*)d_in[4];
    const float* ratio = (const float*)d_in[5];
    float* gamma_out = (float*)d_out;            // B*I*J floats
    float* expanded  = (float*)d_out + NEL;      // B*J*C floats

    float* ws = (float*)d_ws;
    float* Ee = ws;                  // NEL
    float* Wa = ws +   NEL;          // NEL
    float* Wb = ws + 2*NEL;          // NEL
    float* pa = ws + 3*NEL;          // NEL (aliased: e lives here pre-scan)
    float* pb = ws + 4*NEL;          // NEL (j-reversed layout)
    float* ca = ws + 5*NEL;          // BB*II
    float* cb = ws + 5*NEL + BB*II;  // BB*II
    float* e  = pa;                  // e dead once scan_ab starts writing pa

    hipLaunchKernelGGL(energy_kernel, dim3(BB, II/8, JJ/64), dim3(256), 0, stream,
                       text, mel, noise, ratio, e);
    hipLaunchKernelGGL(dscan_kernel, dim3(BB*II), dim3(64), 0, stream, e, Ee, Wa, Wb);
    hipLaunchKernelGGL(scan_ab_kernel, dim3(BB*2), dim3(64), 0, stream,
                       Ee, Wa, Wb, pa, pb, ca, cb);
    hipLaunchKernelGGL(gamma_expand_kernel, dim3(BB*64), dim3(256), 0, stream,
                       pa, pb, ca, cb, text, mmask, gamma_out, expanded);
}

// Round 7
// 129.787 us; speedup vs baseline: 1.2181x; 1.0028x over previous
//
#include <hip/hip_runtime.h>
#include <math.h>

#define BB 2
#define II 128
#define JJ 512
#define CC 256
#define NEL (BB*II*JJ)   // 131072
#define NINF (-INFINITY)
#define K10 4.5399929762484854e-5f   // exp(-10)

typedef float f32x4 __attribute__((ext_vector_type(4)));   // asm-operand-safe vec4

// ---------------- DPP wave64 primitives ----------------
template<int CTRL, int RM = 0xf, int BM = 0xf, bool BC = true>
__device__ __forceinline__ float dppf(float x) {
    return __int_as_float(__builtin_amdgcn_update_dpp(
        0, __float_as_int(x), CTRL, RM, BM, BC));
}
__device__ __forceinline__ float wscan_incl(float x) {
    x += dppf<0x111>(x);              // row_shr:1
    x += dppf<0x112>(x);              // row_shr:2
    x += dppf<0x114>(x);              // row_shr:4
    x += dppf<0x118>(x);              // row_shr:8
    x += dppf<0x142, 0xa>(x);         // row_bcast:15 -> rows 1,3
    x += dppf<0x143, 0xc>(x);         // row_bcast:31 -> rows 2,3
    return x;
}
__device__ __forceinline__ float lane_shr1(float x) { return dppf<0x138>(x); }
__device__ __forceinline__ float bcast63(float x) {
    return __int_as_float(__builtin_amdgcn_readlane(__float_as_int(x), 63));
}

// in-lane inclusive prefix sum, tree form (depth 3)
__device__ __forceinline__ void tree_prefix8(const float x[8], float P[8]) {
    float t[8];
    t[0] = x[0];
    #pragma unroll
    for (int q = 1; q < 8; ++q) t[q] = x[q] + x[q-1];
    float u[8];
    u[0] = t[0]; u[1] = t[1];
    #pragma unroll
    for (int q = 2; q < 8; ++q) u[q] = t[q] + t[q-2];
    P[0] = u[0]; P[1] = u[1]; P[2] = u[2]; P[3] = u[3];
    #pragma unroll
    for (int q = 4; q < 8; ++q) P[q] = u[q] + u[q-4];
}

__device__ __forceinline__ void loadrow8(const float* p, float v[8]) {
    float4 a = *reinterpret_cast<const float4*>(p);
    float4 b = *reinterpret_cast<const float4*>(p + 4);
    v[0]=a.x; v[1]=a.y; v[2]=a.z; v[3]=a.w;
    v[4]=b.x; v[5]=b.y; v[6]=b.z; v[7]=b.w;
}
__device__ __forceinline__ void storerow8(float* __restrict__ p, const float v[8]) {
    *reinterpret_cast<float4*>(p)     = make_float4(v[0],v[1],v[2],v[3]);
    *reinterpret_cast<float4*>(p + 4) = make_float4(v[4],v[5],v[6],v[7]);
}

// ---------------- hand-held vmem ops (invisible to SIInsertWaitcnts) ----------------
// All loop-body vmem is inline asm so the compiler inserts NO vmcnt waits of its
// own (its counting is blind to asm ops and would otherwise drain the pipeline).
__device__ __forceinline__ void aload2(f32x4 &d0, f32x4 &d1, const float* p) {
    asm volatile("global_load_dwordx4 %0, %2, off\n\t"
                 "global_load_dwordx4 %1, %2, off offset:16"
                 : "=&v"(d0), "=&v"(d1) : "v"(p) : "memory");
}
__device__ __forceinline__ void astore2(f32x4 d0, f32x4 d1, float* p) {
    asm volatile("global_store_dwordx4 %2, %0, off\n\t"
                 "global_store_dwordx4 %2, %1, off offset:16"
                 :: "v"(d0), "v"(d1), "v"(p) : "memory");
}
template<int N> __device__ __forceinline__ void waitcnt_vm() {
    asm volatile("s_waitcnt vmcnt(%0)" :: "i"(N) : "memory");
}

struct Buf { f32x4 e0, e1, w0, w1; };   // one (Ee,W) row fragment: 16 VGPRs

// ---------------- energy: tiled outer-product GEMM ----------------
__global__ __launch_bounds__(256) void energy_kernel(
        const float* __restrict__ text, const float* __restrict__ mel,
        const float* __restrict__ noise, const float* __restrict__ ratio,
        float* __restrict__ e) {
    __shared__ float melS[64][65];
    __shared__ float texS[8][65];
    int b  = blockIdx.x;
    int i0 = blockIdx.y * 8;
    int j0 = blockIdx.z * 64;
    int t = threadIdx.x;
    int jj = t & 63, ig = t >> 6;
    float acc0 = 0.f, acc1 = 0.f;
    for (int cc = 0; cc < CC; cc += 64) {
        #pragma unroll
        for (int k = 0; k < 4; ++k) {
            int idx = t + k * 256;
            int row = idx >> 4, seg = idx & 15;
            float4 v = *reinterpret_cast<const float4*>(
                mel + (size_t)(b * JJ + j0 + row) * CC + cc + seg * 4);
            melS[row][seg*4+0] = v.x; melS[row][seg*4+1] = v.y;
            melS[row][seg*4+2] = v.z; melS[row][seg*4+3] = v.w;
        }
        if (t < 128) {
            int row = t >> 4, seg = t & 15;
            float4 v = *reinterpret_cast<const float4*>(
                text + (size_t)(b * II + i0 + row) * CC + cc + seg * 4);
            texS[row][seg*4+0] = v.x; texS[row][seg*4+1] = v.y;
            texS[row][seg*4+2] = v.z; texS[row][seg*4+3] = v.w;
        }
        __syncthreads();
        #pragma unroll 8
        for (int c = 0; c < 64; ++c) {
            float m = melS[jj][c];
            acc0 = fmaf(m, texS[ig*2+0][c], acc0);
            acc1 = fmaf(m, texS[ig*2+1][c], acc1);
        }
        __syncthreads();
    }
    float temp = 0.1f + 0.9f * ratio[0];
    float rtmp = 1.0f / temp;
    int r0 = (b * II + i0 + ig*2 + 0) * JJ + j0 + jj;
    int r1 = (b * II + i0 + ig*2 + 1) * JJ + j0 + jj;
    e[r0] = (acc0 * (1.0f/256.0f) + noise[r0]) * rtmp;
    e[r1] = (acc1 * (1.0f/256.0f) + noise[r1]) * rtmp;
}

// ---------------- per row: Ee = exp(e - rowmax); Wa = 1/suffix_sum; Wb = 1/prefix_sum ----------------
__global__ __launch_bounds__(64) void dscan_kernel(
        const float* __restrict__ e, float* __restrict__ Ee,
        float* __restrict__ Wa, float* __restrict__ Wb) {
    int row = blockIdx.x;
    int lane = threadIdx.x;
    float v[8];
    loadrow8(e + row * JJ + lane * 8, v);
    float m = v[0];
    #pragma unroll
    for (int q = 1; q < 8; ++q) m = fmaxf(m, v[q]);
    #pragma unroll
    for (int d = 1; d < 64; d <<= 1) m = fmaxf(m, __shfl_xor(m, d, 64));
    float x[8];
    #pragma unroll
    for (int q = 0; q < 8; ++q) x[q] = __expf(v[q] - m);
    storerow8(Ee + row * JJ + lane * 8, x);
    float run = 0.f, P[8];
    #pragma unroll
    for (int q = 0; q < 8; ++q) { run += x[q]; P[q] = run; }
    float sc = wscan_incl(run);
    float cp = lane_shr1(sc);
    float run2 = 0.f, S[8];
    #pragma unroll
    for (int q = 7; q >= 0; --q) { run2 += x[q]; S[q] = run2; }
    float sd = run2;
    #pragma unroll
    for (int d = 1; d < 64; d <<= 1) { float o = __shfl_down(sd, d, 64); sd += (lane + d < 64) ? o : 0.0f; }
    float cs = __shfl_down(sd, 1, 64); if (lane == 63) cs = 0.f;
    float wa[8], wb[8];
    #pragma unroll
    for (int q = 0; q < 8; ++q) {
        wa[q] = 1.0f / (S[q] + cs);
        wb[q] = 1.0f / (P[q] + cp);
    }
    storerow8(Wa + row * JJ + lane * 8, wa);
    storerow8(Wb + row * JJ + lane * 8, wb);
}

// ======================= scan_ab: all-asm vmem, reg-resident prefetch d=3 =======================
// Per step, vmem (all inline asm, exact order): [2 stores][4 loads][wait vmcnt(VM)].
// Steady VM=18 == "row i's loads (3 steps old) retired"; warm-up 14/16; drain 14/10/6.
// ca/cb accumulate in LDS (lgkm domain, not in the vmcnt stream).
// p-state rotates depth 4: P regs redefined at step i were stored at step i-3,
// already retired by this step's wait.
// __launch_bounds__(64, 1): 4 waves total on the GPU -- occupancy irrelevant;
// without the ",1" the allocator capped VGPR at 64 (8-wave occupancy target)
// and spilled the Buf ring to scratch, whose vmem ops silently broke both the
// hand-counted vmcnt ledger and the prefetch (R0-R6 all showed VGPR 60-68).

template<bool NORM, int VM, bool PF>
__device__ __forceinline__ void astep(
    int i, int lane, int off,
    const float (&pin)[8], float (&pout)[8], float& c,
    Buf& C, Buf& L,
    const float* __restrict__ EeB, const float* __restrict__ WaB,
    float* __restrict__ paB, float* ldsC)
{
    {
        f32x4 s0 = {pin[0], pin[1], pin[2], pin[3]};
        f32x4 s1 = {pin[4], pin[5], pin[6], pin[7]};
        astore2(s0, s1, paB + (size_t)(i - 1) * JJ + off);   // pin holds row i-1
    }
    if (lane == 0) ldsC[i - 1] = c;
    if (PF) {
        aload2(L.e0, L.e1, EeB + (size_t)(i + 3) * JJ + off);
        aload2(L.w0, L.w1, WaB + (size_t)(i + 3) * JJ + off);
    }
    waitcnt_vm<VM>();
    __builtin_amdgcn_sched_barrier(0);   // rule #18: keep consumers behind the wait
    float CE[8] = {C.e0[0],C.e0[1],C.e0[2],C.e0[3],C.e1[0],C.e1[1],C.e1[2],C.e1[3]};
    float CW[8] = {C.w0[0],C.w0[1],C.w0[2],C.w0[3],C.w1[0],C.w1[1],C.w1[2],C.w1[3]};

    float pup = lane_shr1(pin[7]);
    float y[8];
    y[0] = pup * CW[0];
    #pragma unroll
    for (int q = 1; q < 8; ++q) y[q] = pin[q-1] * CW[q];
    float zz[8];
    #pragma unroll
    for (int q = 0; q < 7; ++q) zz[q] = pin[q];
    zz[7] = (lane == 63) ? 0.0f : pin[7];
    float Y[8], Z[8];
    tree_prefix8(y, Y);
    tree_prefix8(zz, Z);
    float sy = wscan_incl(Y[7]);
    float sz = wscan_incl(Z[7]);
    float oy = lane_shr1(sy);
    float oz = lane_shr1(sz);
    float T  = bcast63(sz);
    #pragma unroll
    for (int q = 0; q < 8; ++q) {
        float S1 = oy + Y[q];                              // incl prefix of y
        float S2 = fmaxf(T - (oz + Z[q]) + zz[q], 0.0f);   // incl suffix of z
        pout[q] = fmaf(CE[q], S1, K10 * S2);
    }
    if (NORM) {
        float Tc = fmaxf(T, 1e-30f);
        float rT = __builtin_amdgcn_rcpf(Tc);
        c += __logf(Tc);
        #pragma unroll
        for (int q = 0; q < 8; ++q) pout[q] *= rT;
    }
}

template<bool NORM, int VM, bool PF>
__device__ __forceinline__ void bstep(
    int i, int lane, int off,
    const float (&pin)[8], float (&pout)[8], float& c,
    Buf& C, Buf& L,
    const float* __restrict__ EeB, const float* __restrict__ WbB,
    float* __restrict__ pbB, float* ldsC)
{
    {
        f32x4 s0 = {pin[0], pin[1], pin[2], pin[3]};
        f32x4 s1 = {pin[4], pin[5], pin[6], pin[7]};
        astore2(s0, s1, pbB + (size_t)(i + 1) * JJ + off);   // pin holds row i+1
    }
    if (lane == 0) ldsC[i + 1] = c;
    if (PF) {
        aload2(L.e0, L.e1, EeB + (size_t)(i - 3) * JJ + 504 - 8 * lane);
        aload2(L.w0, L.w1, WbB + (size_t)(i - 3) * JJ + 504 - 8 * lane);
    }
    waitcnt_vm<VM>();
    __builtin_amdgcn_sched_barrier(0);
    // reversed: CE[q] = rowdata[7-q]  (rowdata[k] = row[504-8*lane+k])
    float CE[8] = {C.e1[3],C.e1[2],C.e1[1],C.e1[0],C.e0[3],C.e0[2],C.e0[1],C.e0[0]};
    float CW[8] = {C.w1[3],C.w1[2],C.w1[1],C.w1[0],C.w0[3],C.w0[2],C.w0[1],C.w0[0]};

    float pup = lane_shr1(pin[7]);
    float pn[8];
    pn[0] = pup;
    #pragma unroll
    for (int q = 1; q < 8; ++q) pn[q] = pin[q-1];
    float w[8];
    #pragma unroll
    for (int q = 0; q < 8; ++q) w[q] = pn[q] * CW[q];
    float W[8], N[8];
    tree_prefix8(w, W);
    tree_prefix8(pn, N);
    float sw = wscan_incl(W[7]);
    float sn = wscan_incl(N[7]);
    float ow = lane_shr1(sw);
    float on = lane_shr1(sn);
    float T  = bcast63(sn);
    #pragma unroll
    for (int q = 0; q < 8; ++q) {
        float QA = ow + W[q];                    // incl prefix of w
        float QB = fmaxf(T - (on + N[q]), 0.0f); // excl suffix of pn
        pout[q] = fmaf(CE[q], QA, K10 * QB);
    }
    if (NORM) {
        float Tc = fmaxf(T, 1e-30f);
        float rT = __builtin_amdgcn_rcpf(Tc);
        c += __logf(Tc);
        #pragma unroll
        for (int q = 0; q < 8; ++q) pout[q] *= rT;
    }
}

__global__ __launch_bounds__(64, 1) void scan_ab_kernel(
        const float* __restrict__ Ee, const float* __restrict__ Wa,
        const float* __restrict__ Wb,
        float* __restrict__ pa, float* __restrict__ pb,
        float* __restrict__ ca, float* __restrict__ cb) {
    __shared__ float ldsC[II];
    int b = blockIdx.x >> 1, dir = blockIdx.x & 1;
    int lane = threadIdx.x, off = lane * 8;
    size_t base = (size_t)b * II * JJ;
    float P0[8], P1[8], P2[8], P3[8], c = 0.0f;
    Buf B0, B1, B2, B3;

    if (dir == 0) {
        const float* EeB = Ee + base; const float* WaB = Wa + base;
        float* paB = pa + base; float* caB = ca + b * II;
        // row 0 via compiler loads (their auto-waits stay ABOVE our asm stream)
        float e0r[8];
        loadrow8(EeB + off, e0r);
        float wa00 = WaB[0];
        #pragma unroll
        for (int q = 0; q < 8; ++q) P0[q] = e0r[q] * wa00;   // row 0
        __builtin_amdgcn_sched_barrier(0);
        // asm prefetch rows 1,2,3 -> B1,B2,B3 (12 vmem ops in flight)
        aload2(B1.e0, B1.e1, EeB + (size_t)1*JJ + off); aload2(B1.w0, B1.w1, WaB + (size_t)1*JJ + off);
        aload2(B2.e0, B2.e1, EeB + (size_t)2*JJ + off); aload2(B2.w0, B2.w1, WaB + (size_t)2*JJ + off);
        aload2(B3.e0, B3.e1, EeB + (size_t)3*JJ + off); aload2(B3.w0, B3.w1, WaB + (size_t)3*JJ + off);
        // warm-up (exact counts)
        astep<true ,14,true>(1, lane, off, P0, P1, c, B1, B0, EeB, WaB, paB, ldsC);
        astep<false,16,true>(2, lane, off, P1, P2, c, B2, B1, EeB, WaB, paB, ldsC);
        #pragma unroll 1
        for (int d = 0; d < 15; ++d) {        // steps 3..122
            int ib = 3 + 8 * d;
            astep<false,18,true>(ib+0, lane, off, P2, P3, c, B3, B2, EeB, WaB, paB, ldsC);
            astep<false,18,true>(ib+1, lane, off, P3, P0, c, B0, B3, EeB, WaB, paB, ldsC);
            astep<true ,18,true>(ib+2, lane, off, P0, P1, c, B1, B0, EeB, WaB, paB, ldsC);
            astep<false,18,true>(ib+3, lane, off, P1, P2, c, B2, B1, EeB, WaB, paB, ldsC);
            astep<false,18,true>(ib+4, lane, off, P2, P3, c, B3, B2, EeB, WaB, paB, ldsC);
            astep<false,18,true>(ib+5, lane, off, P3, P0, c, B0, B3, EeB, WaB, paB, ldsC);
            astep<true ,18,true>(ib+6, lane, off, P0, P1, c, B1, B0, EeB, WaB, paB, ldsC);
            astep<false,18,true>(ib+7, lane, off, P1, P2, c, B2, B1, EeB, WaB, paB, ldsC);
        }
        astep<false,18,true >(123, lane, off, P2, P3, c, B3, B2, EeB, WaB, paB, ldsC);
        astep<false,18,true >(124, lane, off, P3, P0, c, B0, B3, EeB, WaB, paB, ldsC);
        astep<true ,14,false>(125, lane, off, P0, P1, c, B1, B0, EeB, WaB, paB, ldsC);
        astep<false,10,false>(126, lane, off, P1, P2, c, B2, B1, EeB, WaB, paB, ldsC);
        astep<false, 6,false>(127, lane, off, P2, P3, c, B3, B2, EeB, WaB, paB, ldsC);
        storerow8(paB + (size_t)127 * JJ + off, P3);
        if (lane == 0) ldsC[127] = c;
        waitcnt_vm<0>();                       // drain our asm stores before endpgm
        caB[lane]      = ldsC[lane];
        caB[lane + 64] = ldsC[lane + 64];
    } else {
        const float* EeB = Ee + base; const float* WbB = Wb + base;
        float* pbB = pb + base; float* cbB = cb + b * II;
        #pragma unroll
        for (int q = 0; q < 8; ++q) P3[q] = 0.0f;
        P3[0] = (lane == 0) ? 1.0f : 0.0f;   // row 127 (j'=0 <-> orig j=J-1)
        // asm prefetch rows 126,125,124 -> B2,B1,B0 (reversed addressing)
        aload2(B2.e0, B2.e1, EeB + (size_t)126*JJ + 504 - 8*lane); aload2(B2.w0, B2.w1, WbB + (size_t)126*JJ + 504 - 8*lane);
        aload2(B1.e0, B1.e1, EeB + (size_t)125*JJ + 504 - 8*lane); aload2(B1.w0, B1.w1, WbB + (size_t)125*JJ + 504 - 8*lane);
        aload2(B0.e0, B0.e1, EeB + (size_t)124*JJ + 504 - 8*lane); aload2(B0.w0, B0.w1, WbB + (size_t)124*JJ + 504 - 8*lane);
        bstep<true ,14,true>(126, lane, off, P3, P2, c, B2, B3, EeB, WbB, pbB, ldsC);
        bstep<false,16,true>(125, lane, off, P2, P1, c, B1, B2, EeB, WbB, pbB, ldsC);
        #pragma unroll 1
        for (int d = 0; d < 15; ++d) {        // steps 124..5
            int ib = 124 - 8 * d;
            bstep<false,18,true>(ib-0, lane, off, P1, P0, c, B0, B1, EeB, WbB, pbB, ldsC);
            bstep<false,18,true>(ib-1, lane, off, P0, P3, c, B3, B0, EeB, WbB, pbB, ldsC);
            bstep<true ,18,true>(ib-2, lane, off, P3, P2, c, B2, B3, EeB, WbB, pbB, ldsC);
            bstep<false,18,true>(ib-3, lane, off, P2, P1, c, B1, B2, EeB, WbB, pbB, ldsC);
            bstep<false,18,true>(ib-4, lane, off, P1, P0, c, B0, B1, EeB, WbB, pbB, ldsC);
            bstep<false,18,true>(ib-5, lane, off, P0, P3, c, B3, B0, EeB, WbB, pbB, ldsC);
            bstep<true ,18,true>(ib-6, lane, off, P3, P2, c, B2, B3, EeB, WbB, pbB, ldsC);
            bstep<false,18,true>(ib-7, lane, off, P2, P1, c, B1, B2, EeB, WbB, pbB, ldsC);
        }
        bstep<false,18,true >(4, lane, off, P1, P0, c, B0, B1, EeB, WbB, pbB, ldsC);
        bstep<false,18,true >(3, lane, off, P0, P3, c, B3, B0, EeB, WbB, pbB, ldsC);
        bstep<true ,14,false>(2, lane, off, P3, P2, c, B2, B3, EeB, WbB, pbB, ldsC);
        bstep<false,10,false>(1, lane, off, P2, P1, c, B1, B2, EeB, WbB, pbB, ldsC);
        bstep<false, 6,false>(0, lane, off, P1, P0, c, B0, B1, EeB, WbB, pbB, ldsC);
        storerow8(pbB + off, P0);           // row 0
        if (lane == 0) ldsC[0] = c;
        waitcnt_vm<0>();                    // drain our asm stores before endpgm
        cbB[lane]      = ldsC[lane];
        cbB[lane + 64] = ldsC[lane + 64];
    }
}

// ---------------- fused gamma + expand ----------------
__global__ __launch_bounds__(256) void gamma_expand_kernel(
        const float* __restrict__ pa, const float* __restrict__ pb,
        const float* __restrict__ ca, const float* __restrict__ cb,
        const float* __restrict__ text, const float* __restrict__ mmask,
        float* __restrict__ gamma_out, float* __restrict__ expanded) {
    __shared__ float wt[II][9];      // stride 9: phase-A writes ~2-way conflicts (free)
    __shared__ float Ei[II];
    __shared__ float red[8][33];     // partial column sums [q][ic]
    int b   = blockIdx.x >> 6;       // 64 tiles per batch
    int jj0 = (blockIdx.x & 63) * 8;
    int t = threadIdx.x;
    int q = t & 7, ic = t >> 3;      // ic 0..31 handles i = 4*ic..4*ic+3

    if (t < II) Ei[t] = ca[b*II + t] + cb[b*II + t];
    __syncthreads();
    float maxc = Ei[0];
    #pragma unroll 16
    for (int i = 1; i < II; ++i) maxc = fmaxf(maxc, Ei[i]);
    __syncthreads();
    if (t < II) Ei[t] = __expf(Ei[t] - maxc);
    __syncthreads();

    size_t idx0  = (size_t)b * II * JJ + jj0 + q;
    size_t idx0r = (size_t)b * II * JJ + (JJ - 1 - jj0 - q);   // pb stored j-reversed
    float d = 0.f;
    #pragma unroll
    for (int k = 0; k < 4; ++k) {
        int i = ic * 4 + k;
        float P = pa[idx0 + (size_t)i * JJ] * pb[idx0r + (size_t)i * JJ] * Ei[i];
        wt[i][q] = P;
        d += P;
    }
    red[q][ic] = d;
    __syncthreads();
    if (t < 8) {
        float s = 0.f;
        #pragma unroll
        for (int k = 0; k < 32; ++k) s += red[t][k];
        red[t][32] = 1.0f / fmaxf(s, 1e-37f);
    }
    __syncthreads();
    float rD = red[q][32];
    #pragma unroll
    for (int k = 0; k < 4; ++k) {
        int i = ic * 4 + k;
        float P = wt[i][q] * rD;
        wt[i][q] = P;
        gamma_out[idx0 + (size_t)i * JJ] = fmaxf(__logf(P), -1e30f);  // log(0)=-inf -> -1e30
    }
    __syncthreads();

    // phase B: expanded[b, jj0+qq, c=t] = mmask * sum_i wt[i][qq] * text[b,i,t]
    float acc[8] = {0,0,0,0,0,0,0,0};
    const float* txb = text + (size_t)b * II * CC + t;
    #pragma unroll 4
    for (int i = 0; i < II; ++i) {
        float tv = txb[(size_t)i * CC];
        #pragma unroll
        for (int qq = 0; qq < 8; ++qq) acc[qq] = fmaf(wt[i][qq], tv, acc[qq]);
    }
    #pragma unroll
    for (int qq = 0; qq < 8; ++qq) {
        expanded[(size_t)(b * JJ + jj0 + qq) * CC + t] =
            acc[qq] * mmask[b * JJ + jj0 + qq];
    }
}

extern "C" void kernel_launch(void* const* d_in, const int* in_sizes, int n_in,
                              void* d_out, int out_size, void* d_ws, size_t ws_size,
                              hipStream_t stream) {
    const float* text  = (const float*)d_in[0];
    const float* mel   = (const float*)d_in[1];
    const float* mmask = (const float*)d_in[3];
    const float* noise = (const float*)d_in[4];
    const float* ratio = (const float*)d_in[5];
    float* gamma_out = (float*)d_out;            // B*I*J floats
    float* expanded  = (float*)d_out + NEL;      // B*J*C floats

    float* ws = (float*)d_ws;
    float* Ee = ws;                  // NEL
    float* Wa = ws +   NEL;          // NEL
    float* Wb = ws + 2*NEL;          // NEL
    float* pa = ws + 3*NEL;          // NEL (aliased: e lives here pre-scan)
    float* pb = ws + 4*NEL;          // NEL (j-reversed layout)
    float* ca = ws + 5*NEL;          // BB*II
    float* cb = ws + 5*NEL + BB*II;  // BB*II
    float* e  = pa;                  // e dead once scan_ab starts writing pa

    hipLaunchKernelGGL(energy_kernel, dim3(BB, II/8, JJ/64), dim3(256), 0, stream,
                       text, mel, noise, ratio, e);
    hipLaunchKernelGGL(dscan_kernel, dim3(BB*II), dim3(64), 0, stream, e, Ee, Wa, Wb);
    hipLaunchKernelGGL(scan_ab_kernel, dim3(BB*2), dim3(64), 0, stream,
                       Ee, Wa, Wb, pa, pb, ca, cb);
    hipLaunchKernelGGL(gamma_expand_kernel, dim3(BB*64), dim3(256), 0, stream,
                       pa, pb, ca, cb, text, mmask, gamma_out, expanded);
}